// Round 3
// baseline (456.533 us; speedup 1.0000x reference)
//
#include <hip/hip_runtime.h>

#define C2 0.17677669529663687f  // 1/(4*sqrt(2))

// phi(x)[n], x in R^16: n=0 -> 1 ; 1<=n<17 -> x[n-1]/2 ; 17<=n<273 -> x[i]*x[j]*C2 (m=n-17, i=m>>4, j=m&15)
__device__ __forceinline__ float phi_feat(const float* __restrict__ v16, int n) {
    if (n == 0) return 1.0f;
    if (n < 17) return v16[n - 1] * 0.5f;
    int m = n - 17;
    return v16[m >> 4] * v16[m & 15] * C2;
}

// ---------------- tiled GEMM: hidden(1024x768) @ [Wq|Wk|Wv] -> qkv(1024x1152) ----------------
__global__ __launch_bounds__(256) void gemm_qkv_k(
    const float* __restrict__ H, const float* __restrict__ Wq,
    const float* __restrict__ Wk, const float* __restrict__ Wv,
    float* __restrict__ out)
{
    const int nt = blockIdx.x, mt = blockIdx.y;
    const float* W; int ldw, colbase;
    if (nt < 3)      { W = Wq; ldw = 192; colbase = nt * 64; }
    else if (nt < 6) { W = Wk; ldw = 192; colbase = (nt - 3) * 64; }
    else             { W = Wv; ldw = 768; colbase = (nt - 6) * 64; }
    __shared__ float At[64][68];   // [k][m]
    __shared__ float Bs[64][68];   // [k][n]
    const int tid = threadIdx.x;
    const int tj = tid & 15, ti = tid >> 4;
    float acc[4][4] = {};
    const int row0 = mt * 64;
    for (int k0 = 0; k0 < 768; k0 += 64) {
        #pragma unroll
        for (int l = 0; l < 4; ++l) {
            int idx = tid + l * 256;
            int r = idx >> 4, c4 = (idx & 15) * 4;
            float4 a = *(const float4*)&H[(row0 + r) * 768 + k0 + c4];
            At[c4 + 0][r] = a.x; At[c4 + 1][r] = a.y;
            At[c4 + 2][r] = a.z; At[c4 + 3][r] = a.w;
            *(float4*)&Bs[r][c4] = *(const float4*)&W[(k0 + r) * ldw + colbase + c4];
        }
        __syncthreads();
        #pragma unroll
        for (int kk = 0; kk < 64; ++kk) {
            float4 a = *(const float4*)&At[kk][ti * 4];
            float4 b = *(const float4*)&Bs[kk][tj * 4];
            acc[0][0] += a.x * b.x; acc[0][1] += a.x * b.y; acc[0][2] += a.x * b.z; acc[0][3] += a.x * b.w;
            acc[1][0] += a.y * b.x; acc[1][1] += a.y * b.y; acc[1][2] += a.y * b.z; acc[1][3] += a.y * b.w;
            acc[2][0] += a.z * b.x; acc[2][1] += a.z * b.y; acc[2][2] += a.z * b.z; acc[2][3] += a.z * b.w;
            acc[3][0] += a.w * b.x; acc[3][1] += a.w * b.y; acc[3][2] += a.w * b.z; acc[3][3] += a.w * b.w;
        }
        __syncthreads();
    }
    #pragma unroll
    for (int ii = 0; ii < 4; ++ii) {
        float4 v = make_float4(acc[ii][0], acc[ii][1], acc[ii][2], acc[ii][3]);
        *(float4*)&out[(row0 + ti * 4 + ii) * 1152 + nt * 64 + tj * 4] = v;
    }
}

// ---------------- tiled GEMM: y(1024x768) @ Wo(768x768) -> out(1024x768) ----------------
__global__ __launch_bounds__(256) void gemm_wo_k(
    const float* __restrict__ Y, const float* __restrict__ Wo, float* __restrict__ out)
{
    const int nt = blockIdx.x, mt = blockIdx.y;
    __shared__ float At[64][68];
    __shared__ float Bs[64][68];
    const int tid = threadIdx.x;
    const int tj = tid & 15, ti = tid >> 4;
    float acc[4][4] = {};
    const int row0 = mt * 64, colbase = nt * 64;
    for (int k0 = 0; k0 < 768; k0 += 64) {
        #pragma unroll
        for (int l = 0; l < 4; ++l) {
            int idx = tid + l * 256;
            int r = idx >> 4, c4 = (idx & 15) * 4;
            float4 a = *(const float4*)&Y[(row0 + r) * 768 + k0 + c4];
            At[c4 + 0][r] = a.x; At[c4 + 1][r] = a.y;
            At[c4 + 2][r] = a.z; At[c4 + 3][r] = a.w;
            *(float4*)&Bs[r][c4] = *(const float4*)&Wo[(k0 + r) * 768 + colbase + c4];
        }
        __syncthreads();
        #pragma unroll
        for (int kk = 0; kk < 64; ++kk) {
            float4 a = *(const float4*)&At[kk][ti * 4];
            float4 b = *(const float4*)&Bs[kk][tj * 4];
            acc[0][0] += a.x * b.x; acc[0][1] += a.x * b.y; acc[0][2] += a.x * b.z; acc[0][3] += a.x * b.w;
            acc[1][0] += a.y * b.x; acc[1][1] += a.y * b.y; acc[1][2] += a.y * b.z; acc[1][3] += a.y * b.w;
            acc[2][0] += a.z * b.x; acc[2][1] += a.z * b.y; acc[2][2] += a.z * b.z; acc[2][3] += a.z * b.w;
            acc[3][0] += a.w * b.x; acc[3][1] += a.w * b.y; acc[3][2] += a.w * b.z; acc[3][3] += a.w * b.w;
        }
        __syncthreads();
    }
    #pragma unroll
    for (int ii = 0; ii < 4; ++ii) {
        float4 v = make_float4(acc[ii][0], acc[ii][1], acc[ii][2], acc[ii][3]);
        *(float4*)&out[(row0 + ti * 4 + ii) * 768 + colbase + tj * 4] = v;
    }
}

// ---------------- per-chunk state: S[h][c][n][d] = sum_s phi_n(k_s) v_s[d];  z[h][c][n] = sum_s phi_n(k_s) ----------------
// grid (273, 16, 12), block 64 (thread = d)
__global__ __launch_bounds__(64) void state_simple(
    const float* __restrict__ qkv, float* __restrict__ S, float* __restrict__ z)
{
    int n = blockIdx.x, c = blockIdx.y, h = blockIdx.z;
    int d = threadIdx.x;
    float acc = 0.f, zacc = 0.f;
    for (int s = 0; s < 64; ++s) {
        const float* kv = &qkv[(size_t)(c * 64 + s) * 1152 + 192 + h * 16];
        float ph = phi_feat(kv, n);
        acc  += ph * qkv[(size_t)(c * 64 + s) * 1152 + 384 + h * 64 + d];
        zacc += ph;
    }
    S[((size_t)(h * 16 + c) * 273 + n) * 64 + d] = acc;
    if (d == 0) z[(h * 16 + c) * 273 + n] = zacc;
}

// ---------------- exclusive prefix over 16 chunks (in place) ----------------
__global__ __launch_bounds__(256) void scan_state_k(float* __restrict__ S, float* __restrict__ z)
{
    const int NS = 12 * 273 * 64;   // threads for S part (each loops over 16 chunks)
    int e = blockIdx.x * 256 + threadIdx.x;
    if (e < NS) {
        int hh = e / (273 * 64), rem = e % (273 * 64);
        float* p = S + (size_t)hh * 16 * 273 * 64 + rem;
        float run = 0.f;
        #pragma unroll
        for (int c = 0; c < 16; ++c) { float v = p[c * 273 * 64]; p[c * 273 * 64] = run; run += v; }
    } else if (e < NS + 12 * 273) {
        int e2 = e - NS, hh = e2 / 273, n = e2 % 273;
        float* p = z + hh * 16 * 273 + n;
        float run = 0.f;
        #pragma unroll
        for (int c = 0; c < 16; ++c) { float v = p[c * 273]; p[c * 273] = run; run += v; }
    }
}

// ---------------- per-position output ----------------
// grid (64, 16, 12) = (i, c, h), block 64 (thread = d)
__global__ __launch_bounds__(64) void out_simple(
    const float* __restrict__ qkv, const float* __restrict__ S, const float* __restrict__ z,
    float* __restrict__ y)
{
    int i = blockIdx.x, c = blockIdx.y, h = blockIdx.z;
    int d = threadIdx.x;
    int t = c * 64 + i;
    const float* qv = &qkv[(size_t)t * 1152 + h * 16];
    const float* Sb = &S[(size_t)(h * 16 + c) * 273 * 64];
    const float* zb = &z[(h * 16 + c) * 273];
    float num = 0.f, den = 1e-12f;
    for (int n = 0; n < 273; ++n) {
        float ph = phi_feat(qv, n);
        num += ph * Sb[n * 64 + d];
        den += ph * zb[n];
    }
    for (int j = 0; j <= i; ++j) {
        const float* kv = &qkv[(size_t)(c * 64 + j) * 1152 + 192 + h * 16];
        float u = 0.f;
        #pragma unroll
        for (int f = 0; f < 16; ++f) u += qv[f] * kv[f];
        float sc = 1.f + 0.25f * u + u * u * (1.f / 32.f);
        num += sc * qkv[(size_t)(c * 64 + j) * 1152 + 384 + h * 64 + d];
        den += sc;
    }
    y[(size_t)t * 768 + h * 64 + d] = num / den;
}

extern "C" void kernel_launch(void* const* d_in, const int* in_sizes, int n_in,
                              void* d_out, int out_size, void* d_ws, size_t ws_size,
                              hipStream_t stream) {
    const float* hs = (const float*)d_in[0];
    const float* Wq = (const float*)d_in[1];
    const float* Wk = (const float*)d_in[2];
    const float* Wv = (const float*)d_in[3];
    const float* Wo = (const float*)d_in[4];
    float* out = (float*)d_out;
    float* ws  = (float*)d_ws;

    // Workspace layout (fixed: 12*16*273*64 = 3,354,624 — NOT 2,795,520 as rounds 1-2 wrongly used,
    // which made zb overlap S for heads >= 10 and race in the scan).
    float* qkv = ws;                   // 1024*1152      = 1,179,648 floats
    float* yb  = ws + 1179648;         // 1024*768       =   786,432
    float* Sb  = ws + 1966080;         // 12*16*273*64   = 3,354,624
    float* zb  = ws + 5320704;         // 12*16*273      =    52,416
    // total 5,373,120 floats = 21.5 MB

    gemm_qkv_k   <<<dim3(18, 16), 256, 0, stream>>>(hs, Wq, Wk, Wv, qkv);
    state_simple <<<dim3(273, 16, 12), 64, 0, stream>>>(qkv, Sb, zb);
    scan_state_k <<<832, 256, 0, stream>>>(Sb, zb);
    out_simple   <<<dim3(64, 16, 12), 64, 0, stream>>>(qkv, Sb, zb, yb);
    gemm_wo_k    <<<dim3(12, 16), 256, 0, stream>>>(yb, Wo, out);
}

// Round 4
// 206.600 us; speedup vs baseline: 2.2097x; 2.2097x over previous
//
#include <hip/hip_runtime.h>

#define C2 0.17677669529663687f  // 1/(4*sqrt(2))

// ---------------- tiled GEMM: hidden(1024x768) @ [Wq|Wk|Wv] -> qkv(1024x1152) ----------------
__global__ __launch_bounds__(256) void gemm_qkv_k(
    const float* __restrict__ H, const float* __restrict__ Wq,
    const float* __restrict__ Wk, const float* __restrict__ Wv,
    float* __restrict__ out)
{
    const int nt = blockIdx.x, mt = blockIdx.y;
    const float* W; int ldw, colbase;
    if (nt < 3)      { W = Wq; ldw = 192; colbase = nt * 64; }
    else if (nt < 6) { W = Wk; ldw = 192; colbase = (nt - 3) * 64; }
    else             { W = Wv; ldw = 768; colbase = (nt - 6) * 64; }
    __shared__ float At[64][68];   // [k][m]
    __shared__ float Bs[64][68];   // [k][n]
    const int tid = threadIdx.x;
    const int tj = tid & 15, ti = tid >> 4;
    float acc[4][4] = {};
    const int row0 = mt * 64;
    for (int k0 = 0; k0 < 768; k0 += 64) {
        #pragma unroll
        for (int l = 0; l < 4; ++l) {
            int idx = tid + l * 256;
            int r = idx >> 4, c4 = (idx & 15) * 4;
            float4 a = *(const float4*)&H[(row0 + r) * 768 + k0 + c4];
            At[c4 + 0][r] = a.x; At[c4 + 1][r] = a.y;
            At[c4 + 2][r] = a.z; At[c4 + 3][r] = a.w;
            *(float4*)&Bs[r][c4] = *(const float4*)&W[(k0 + r) * ldw + colbase + c4];
        }
        __syncthreads();
        #pragma unroll
        for (int kk = 0; kk < 64; ++kk) {
            float4 a = *(const float4*)&At[kk][ti * 4];
            float4 b = *(const float4*)&Bs[kk][tj * 4];
            acc[0][0] += a.x * b.x; acc[0][1] += a.x * b.y; acc[0][2] += a.x * b.z; acc[0][3] += a.x * b.w;
            acc[1][0] += a.y * b.x; acc[1][1] += a.y * b.y; acc[1][2] += a.y * b.z; acc[1][3] += a.y * b.w;
            acc[2][0] += a.z * b.x; acc[2][1] += a.z * b.y; acc[2][2] += a.z * b.z; acc[2][3] += a.z * b.w;
            acc[3][0] += a.w * b.x; acc[3][1] += a.w * b.y; acc[3][2] += a.w * b.z; acc[3][3] += a.w * b.w;
        }
        __syncthreads();
    }
    #pragma unroll
    for (int ii = 0; ii < 4; ++ii) {
        float4 v = make_float4(acc[ii][0], acc[ii][1], acc[ii][2], acc[ii][3]);
        *(float4*)&out[(row0 + ti * 4 + ii) * 1152 + nt * 64 + tj * 4] = v;
    }
}

// ---------------- tiled GEMM: y(1024x768) @ Wo(768x768) -> out(1024x768) ----------------
__global__ __launch_bounds__(256) void gemm_wo_k(
    const float* __restrict__ Y, const float* __restrict__ Wo, float* __restrict__ out)
{
    const int nt = blockIdx.x, mt = blockIdx.y;
    __shared__ float At[64][68];
    __shared__ float Bs[64][68];
    const int tid = threadIdx.x;
    const int tj = tid & 15, ti = tid >> 4;
    float acc[4][4] = {};
    const int row0 = mt * 64, colbase = nt * 64;
    for (int k0 = 0; k0 < 768; k0 += 64) {
        #pragma unroll
        for (int l = 0; l < 4; ++l) {
            int idx = tid + l * 256;
            int r = idx >> 4, c4 = (idx & 15) * 4;
            float4 a = *(const float4*)&Y[(row0 + r) * 768 + k0 + c4];
            At[c4 + 0][r] = a.x; At[c4 + 1][r] = a.y;
            At[c4 + 2][r] = a.z; At[c4 + 3][r] = a.w;
            *(float4*)&Bs[r][c4] = *(const float4*)&Wo[(k0 + r) * 768 + colbase + c4];
        }
        __syncthreads();
        #pragma unroll
        for (int kk = 0; kk < 64; ++kk) {
            float4 a = *(const float4*)&At[kk][ti * 4];
            float4 b = *(const float4*)&Bs[kk][tj * 4];
            acc[0][0] += a.x * b.x; acc[0][1] += a.x * b.y; acc[0][2] += a.x * b.z; acc[0][3] += a.x * b.w;
            acc[1][0] += a.y * b.x; acc[1][1] += a.y * b.y; acc[1][2] += a.y * b.z; acc[1][3] += a.y * b.w;
            acc[2][0] += a.z * b.x; acc[2][1] += a.z * b.y; acc[2][2] += a.z * b.z; acc[2][3] += a.z * b.w;
            acc[3][0] += a.w * b.x; acc[3][1] += a.w * b.y; acc[3][2] += a.w * b.z; acc[3][3] += a.w * b.w;
        }
        __syncthreads();
    }
    #pragma unroll
    for (int ii = 0; ii < 4; ++ii) {
        float4 v = make_float4(acc[ii][0], acc[ii][1], acc[ii][2], acc[ii][3]);
        *(float4*)&out[(row0 + ti * 4 + ii) * 768 + colbase + tj * 4] = v;
    }
}

// ---------------- per-chunk state (tiled): S[h][c] = phi(K_c)^T @ V_c (273x64), z = colsum phi ----------------
// grid (16, 12), block 256
__global__ __launch_bounds__(256) void chunk_state_k(
    const float* __restrict__ qkv, float* __restrict__ S, float* __restrict__ z)
{
    const int c = blockIdx.x, h = blockIdx.y;
    __shared__ float Kc[64][16];
    __shared__ float Vc[64][64];
    const int tid = threadIdx.x;
    {
        int s = tid >> 2, f4 = (tid & 3) * 4;
        *(float4*)&Kc[s][f4] = *(const float4*)&qkv[(size_t)(c * 64 + s) * 1152 + 192 + h * 16 + f4];
    }
    #pragma unroll
    for (int l = 0; l < 4; ++l) {
        int idx = tid + l * 256;
        int s = idx >> 4, d4 = (idx & 15) * 4;
        *(float4*)&Vc[s][d4] = *(const float4*)&qkv[(size_t)(c * 64 + s) * 1152 + 384 + h * 64 + d4];
    }
    __syncthreads();
    const int td = tid & 15, tg = tid >> 4;
    float acc[16][4] = {};
    float acce[4] = {}, acce2[4] = {};
    for (int s = 0; s < 64; ++s) {
        float kf = Kc[s][tg];
        float4 vv = *(const float4*)&Vc[s][td * 4];
        float4 k0 = *(const float4*)&Kc[s][0];
        float4 k1 = *(const float4*)&Kc[s][4];
        float4 k2 = *(const float4*)&Kc[s][8];
        float4 k3 = *(const float4*)&Kc[s][12];
        float kv[16] = {k0.x,k0.y,k0.z,k0.w, k1.x,k1.y,k1.z,k1.w,
                        k2.x,k2.y,k2.z,k2.w, k3.x,k3.y,k3.z,k3.w};
        float kprev = (tg == 0) ? 0.f : kv[tg - 1];
        float ev  = (tg == 0) ? 1.0f : kprev * 0.5f;   // phi row n = tg
        float ev2 = kv[15] * 0.5f;                      // phi row n = 16
        acce[0]  += ev  * vv.x; acce[1]  += ev  * vv.y; acce[2]  += ev  * vv.z; acce[3]  += ev  * vv.w;
        acce2[0] += ev2 * vv.x; acce2[1] += ev2 * vv.y; acce2[2] += ev2 * vv.z; acce2[3] += ev2 * vv.w;
        #pragma unroll
        for (int j = 0; j < 16; ++j) {
            float w = kf * kv[j] * C2;  // phi row n = 17 + tg*16 + j
            acc[j][0] += w * vv.x; acc[j][1] += w * vv.y;
            acc[j][2] += w * vv.z; acc[j][3] += w * vv.w;
        }
    }
    float* Sb = S + (size_t)((h * 16 + c) * 273) * 64;
    #pragma unroll
    for (int j = 0; j < 16; ++j) {
        float4 v = make_float4(acc[j][0], acc[j][1], acc[j][2], acc[j][3]);
        *(float4*)&Sb[(17 + tg * 16 + j) * 64 + td * 4] = v;
    }
    {
        float4 v = make_float4(acce[0], acce[1], acce[2], acce[3]);
        *(float4*)&Sb[tg * 64 + td * 4] = v;   // rows 0..15
    }
    if (tg == 15) {
        float4 v = make_float4(acce2[0], acce2[1], acce2[2], acce2[3]);
        *(float4*)&Sb[16 * 64 + td * 4] = v;   // row 16
    }
    // z rows
    float* zb = z + (h * 16 + c) * 273;
    for (int n = tid; n < 273; n += 256) {
        float zv = 0.f;
        if (n == 0) zv = 64.0f;
        else if (n < 17) { for (int s = 0; s < 64; ++s) zv += Kc[s][n - 1]; zv *= 0.5f; }
        else {
            int m = n - 17, f1 = m >> 4, f2 = m & 15;
            for (int s = 0; s < 64; ++s) zv += Kc[s][f1] * Kc[s][f2];
            zv *= C2;
        }
        zb[n] = zv;
    }
}

// ---------------- exclusive prefix over 16 chunks (in place) ----------------
__global__ __launch_bounds__(256) void scan_state_k(float* __restrict__ S, float* __restrict__ z)
{
    const int NS = 12 * 273 * 64;
    int e = blockIdx.x * 256 + threadIdx.x;
    if (e < NS) {
        int hh = e / (273 * 64), rem = e % (273 * 64);
        float* p = S + (size_t)hh * 16 * 273 * 64 + rem;
        float run = 0.f;
        #pragma unroll
        for (int c = 0; c < 16; ++c) { float v = p[c * 273 * 64]; p[c * 273 * 64] = run; run += v; }
    } else if (e < NS + 12 * 273) {
        int e2 = e - NS, hh = e2 / 273, n = e2 % 273;
        float* p = z + hh * 16 * 273 + n;
        float run = 0.f;
        #pragma unroll
        for (int c = 0; c < 16; ++c) { float v = p[c * 273]; p[c * 273] = run; run += v; }
    }
}

// ---------------- per-chunk output (tiled): intra (poly causal) + inter (phi(Q)@S_prefix) ----------------
// grid (16, 12), block 256
__global__ __launch_bounds__(256) void chunk_out_k(
    const float* __restrict__ qkv, const float* __restrict__ S, const float* __restrict__ z,
    float* __restrict__ y)
{
    const int c = blockIdx.x, h = blockIdx.y;
    __shared__ float Qc[64][17];
    __shared__ float Kc[64][17];
    __shared__ float Vc[64][64];
    __shared__ float Al[64][65];
    __shared__ float St[64][64];
    __shared__ float zl[273];
    __shared__ float dpart[4][64];
    __shared__ float denl[64];
    const int tid = threadIdx.x;
    {
        int s = tid >> 2, f4 = (tid & 3) * 4;
        float4 qv = *(const float4*)&qkv[(size_t)(c * 64 + s) * 1152 + h * 16 + f4];
        Qc[s][f4] = qv.x; Qc[s][f4 + 1] = qv.y; Qc[s][f4 + 2] = qv.z; Qc[s][f4 + 3] = qv.w;
        float4 kv = *(const float4*)&qkv[(size_t)(c * 64 + s) * 1152 + 192 + h * 16 + f4];
        Kc[s][f4] = kv.x; Kc[s][f4 + 1] = kv.y; Kc[s][f4 + 2] = kv.z; Kc[s][f4 + 3] = kv.w;
    }
    #pragma unroll
    for (int l = 0; l < 4; ++l) {
        int idx = tid + l * 256;
        int s = idx >> 4, d4 = (idx & 15) * 4;
        *(float4*)&Vc[s][d4] = *(const float4*)&qkv[(size_t)(c * 64 + s) * 1152 + 384 + h * 64 + d4];
    }
    const float* zb = z + (h * 16 + c) * 273;
    for (int n = tid; n < 273; n += 256) zl[n] = zb[n];
    __syncthreads();

    const int tj = tid & 15, ti = tid >> 4;
    float qreg[4][16];
    #pragma unroll
    for (int ii = 0; ii < 4; ++ii)
        #pragma unroll
        for (int f = 0; f < 16; ++f) qreg[ii][f] = Qc[ti * 4 + ii][f];

    // A = score(Q K^T) with causal mask
    {
        float a[4][4] = {};
        #pragma unroll
        for (int f = 0; f < 16; ++f) {
            float kb[4];
            #pragma unroll
            for (int jj = 0; jj < 4; ++jj) kb[jj] = Kc[tj * 4 + jj][f];
            #pragma unroll
            for (int ii = 0; ii < 4; ++ii)
                #pragma unroll
                for (int jj = 0; jj < 4; ++jj) a[ii][jj] += qreg[ii][f] * kb[jj];
        }
        #pragma unroll
        for (int ii = 0; ii < 4; ++ii)
            #pragma unroll
            for (int jj = 0; jj < 4; ++jj) {
                int i = ti * 4 + ii, j = tj * 4 + jj;
                float av = a[ii][jj];
                float sc = 1.f + 0.25f * av + av * av * (1.f / 32.f);
                Al[i][j] = (j <= i) ? sc : 0.f;
            }
    }
    __syncthreads();

    // denominator: inter partials (one n-range per wave) + intra row-sum
    {
        int i = tid & 63, p = tid >> 6;
        int ns = (p * 273) >> 2, ne = ((p + 1) * 273) >> 2;
        float dp = 0.f;
        for (int n = ns; n < ne; ++n) {
            float ph;
            if (n == 0) ph = 1.f;
            else if (n < 17) ph = Qc[i][n - 1] * 0.5f;
            else { int m = n - 17; ph = Qc[i][m >> 4] * Qc[i][m & 15] * C2; }
            dp += ph * zl[n];
        }
        if (p == 0) { float di = 0.f; for (int j = 0; j < 64; ++j) di += Al[i][j]; dp += di; }
        dpart[p][i] = dp;
    }
    __syncthreads();
    if (tid < 64) denl[tid] = dpart[0][tid] + dpart[1][tid] + dpart[2][tid] + dpart[3][tid] + 1e-12f;

    float acc[4][4] = {};
    // intra: score @ V
    for (int j = 0; j < 64; ++j) {
        float4 vv = *(const float4*)&Vc[j][tj * 4];
        float aa[4];
        #pragma unroll
        for (int ii = 0; ii < 4; ++ii) aa[ii] = Al[ti * 4 + ii][j];
        #pragma unroll
        for (int ii = 0; ii < 4; ++ii) {
            acc[ii][0] += aa[ii] * vv.x; acc[ii][1] += aa[ii] * vv.y;
            acc[ii][2] += aa[ii] * vv.z; acc[ii][3] += aa[ii] * vv.w;
        }
    }
    // inter rows 0..16 (const + linear)
    const float* Sb = S + (size_t)((h * 16 + c) * 273) * 64;
    for (int idx = tid; idx < 17 * 64; idx += 256) St[idx >> 6][idx & 63] = Sb[idx];
    __syncthreads();
    #pragma unroll
    for (int n = 0; n < 17; ++n) {
        float4 sv = *(const float4*)&St[n][tj * 4];
        float w[4];
        #pragma unroll
        for (int ii = 0; ii < 4; ++ii) w[ii] = (n == 0) ? 1.f : qreg[ii][n - 1] * 0.5f;
        #pragma unroll
        for (int ii = 0; ii < 4; ++ii) {
            acc[ii][0] += w[ii] * sv.x; acc[ii][1] += w[ii] * sv.y;
            acc[ii][2] += w[ii] * sv.z; acc[ii][3] += w[ii] * sv.w;
        }
    }
    // quadratic rows 17..272 in 4 tiles of 64
    #pragma unroll
    for (int t = 0; t < 4; ++t) {
        __syncthreads();
        #pragma unroll
        for (int l = 0; l < 4; ++l) {
            int idx = tid + l * 256;
            int r = idx >> 4, d4 = (idx & 15) * 4;
            *(float4*)&St[r][d4] = *(const float4*)&Sb[(17 + t * 64 + r) * 64 + d4];
        }
        __syncthreads();
        #pragma unroll
        for (int b1 = 0; b1 < 4; ++b1) {
            int f1 = t * 4 + b1;
            float qf[4];
            #pragma unroll
            for (int ii = 0; ii < 4; ++ii) qf[ii] = qreg[ii][f1] * C2;
            #pragma unroll
            for (int f2 = 0; f2 < 16; ++f2) {
                int nn = b1 * 16 + f2;
                float4 sv = *(const float4*)&St[nn][tj * 4];
                float w[4];
                #pragma unroll
                for (int ii = 0; ii < 4; ++ii) w[ii] = qf[ii] * qreg[ii][f2];
                #pragma unroll
                for (int ii = 0; ii < 4; ++ii) {
                    acc[ii][0] += w[ii] * sv.x; acc[ii][1] += w[ii] * sv.y;
                    acc[ii][2] += w[ii] * sv.z; acc[ii][3] += w[ii] * sv.w;
                }
            }
        }
    }
    #pragma unroll
    for (int ii = 0; ii < 4; ++ii) {
        int i = ti * 4 + ii;
        float dn = denl[i];
        float4 o = make_float4(acc[ii][0] / dn, acc[ii][1] / dn, acc[ii][2] / dn, acc[ii][3] / dn);
        *(float4*)&y[(size_t)(c * 64 + i) * 768 + h * 64 + tj * 4] = o;
    }
}

extern "C" void kernel_launch(void* const* d_in, const int* in_sizes, int n_in,
                              void* d_out, int out_size, void* d_ws, size_t ws_size,
                              hipStream_t stream) {
    const float* hs = (const float*)d_in[0];
    const float* Wq = (const float*)d_in[1];
    const float* Wk = (const float*)d_in[2];
    const float* Wv = (const float*)d_in[3];
    const float* Wo = (const float*)d_in[4];
    float* out = (float*)d_out;
    float* ws  = (float*)d_ws;

    // Workspace layout (12*16*273*64 = 3,354,624 — do NOT change without re-deriving; rounds 1-2
    // failed solely because zb overlapped Sb).
    float* qkv = ws;                   // 1024*1152      = 1,179,648 floats
    float* yb  = ws + 1179648;         // 1024*768       =   786,432
    float* Sb  = ws + 1966080;         // 12*16*273*64   = 3,354,624
    float* zb  = ws + 5320704;         // 12*16*273      =    52,416
    // total 5,373,120 floats = 21.5 MB

    gemm_qkv_k   <<<dim3(18, 16), 256, 0, stream>>>(hs, Wq, Wk, Wv, qkv);
    chunk_state_k<<<dim3(16, 12), 256, 0, stream>>>(qkv, Sb, zb);
    scan_state_k <<<832, 256, 0, stream>>>(Sb, zb);
    chunk_out_k  <<<dim3(16, 12), 256, 0, stream>>>(qkv, Sb, zb, yb);
    gemm_wo_k    <<<dim3(12, 16), 256, 0, stream>>>(yb, Wo, out);
}

// Round 5
// 196.056 us; speedup vs baseline: 2.3286x; 1.0538x over previous
//
#include <hip/hip_runtime.h>

#define C2 0.17677669529663687f  // 1/(4*sqrt(2))

typedef __attribute__((ext_vector_type(8))) short short8;
typedef __attribute__((ext_vector_type(4))) float f32x4;

// fp32 -> bf16 round-to-nearest-even
__device__ __forceinline__ unsigned short f2bf(float x) {
    union { float f; unsigned u; } v; v.f = x;
    unsigned r = v.u + 0x7fffu + ((v.u >> 16) & 1u);
    return (unsigned short)(r >> 16);
}

// ---------------- MFMA GEMM body (64x64 block tile, 4 waves of 32x32, BK=32) ----------------
// A fp32 [M x 768] row-major; W fp32 [768 x ldw] row-major; out fp32 [M x outld].
// Fragment layouts per cdna_hip_programming.md §3 (verified m89/m92):
//   A-frag: A[m=lane&15][k=quad*8+j], B-frag: B[k=quad*8+j][n=lane&15] (stored transposed [n][k] in LDS)
//   C/D: col=lane&15, row=quad*4+reg
// B LDS k-chunk XOR-swizzled by (n>>4)&3: transpose-writes 2-way (free), frag reads conflict-free.
__device__ __forceinline__ void gemm_mfma_body(
    const float* __restrict__ A, const float* __restrict__ W,
    float* __restrict__ out, int row0, int n0, int outcol0, int ldw, int outld)
{
    __shared__ unsigned short Al[64][40];
    __shared__ unsigned short Bl[64][40];
    const int tid = threadIdx.x;
    const int lane = tid & 63;
    const int wave = tid >> 6;
    const int wm = wave & 1, wn = wave >> 1;
    const int quad = lane >> 4, lr = lane & 15;

    f32x4 acc[2][2] = {{{0.f,0.f,0.f,0.f},{0.f,0.f,0.f,0.f}},
                       {{0.f,0.f,0.f,0.f},{0.f,0.f,0.f,0.f}}};

    for (int k0 = 0; k0 < 768; k0 += 32) {
        // stage A: 64 rows x 32 k  (512 float4, 2 per thread)
        #pragma unroll
        for (int l = 0; l < 2; ++l) {
            int idx = tid + l * 256;
            int r = idx >> 3, kq = (idx & 7) * 4;
            float4 a = *(const float4*)&A[(size_t)(row0 + r) * 768 + k0 + kq];
            ushort4 b = make_ushort4(f2bf(a.x), f2bf(a.y), f2bf(a.z), f2bf(a.w));
            *(ushort4*)&Al[r][kq] = b;
        }
        // stage B transposed: Bl[n][k-swizzled]
        #pragma unroll
        for (int l = 0; l < 2; ++l) {
            int idx = tid + l * 256;
            int kr = idx >> 4, nq = (idx & 15) * 4;
            float4 b = *(const float4*)&W[(size_t)(k0 + kr) * ldw + n0 + nq];
            int col = ((((kr >> 3) ^ ((idx & 15) >> 2)) << 3)) | (kr & 7);
            Bl[nq + 0][col] = f2bf(b.x);
            Bl[nq + 1][col] = f2bf(b.y);
            Bl[nq + 2][col] = f2bf(b.z);
            Bl[nq + 3][col] = f2bf(b.w);
        }
        __syncthreads();
        short8 af[2], bf[2];
        #pragma unroll
        for (int mi = 0; mi < 2; ++mi)
            af[mi] = *(const short8*)&Al[wm * 32 + mi * 16 + lr][quad << 3];
        #pragma unroll
        for (int ni = 0; ni < 2; ++ni) {
            int csw = quad ^ ((wn * 2 + ni) & 3);
            bf[ni] = *(const short8*)&Bl[wn * 32 + ni * 16 + lr][csw << 3];
        }
        #pragma unroll
        for (int mi = 0; mi < 2; ++mi)
            #pragma unroll
            for (int ni = 0; ni < 2; ++ni)
                acc[mi][ni] = __builtin_amdgcn_mfma_f32_16x16x32_bf16(af[mi], bf[ni], acc[mi][ni], 0, 0, 0);
        __syncthreads();
    }
    #pragma unroll
    for (int mi = 0; mi < 2; ++mi)
        #pragma unroll
        for (int ni = 0; ni < 2; ++ni)
            #pragma unroll
            for (int r = 0; r < 4; ++r)
                out[(size_t)(row0 + wm * 32 + mi * 16 + quad * 4 + r) * outld
                    + outcol0 + wn * 32 + ni * 16 + lr] = acc[mi][ni][r];
}

// qkv: hidden(1024x768) @ [Wq|Wk|Wv] -> qkv(1024x1152). grid (18,16)
__global__ __launch_bounds__(256) void gemm_qkv_mfma(
    const float* __restrict__ H, const float* __restrict__ Wq,
    const float* __restrict__ Wk, const float* __restrict__ Wv,
    float* __restrict__ out)
{
    const int nt = blockIdx.x, mt = blockIdx.y;
    const float* W; int ldw, n0;
    if (nt < 3)      { W = Wq; ldw = 192; n0 = nt * 64; }
    else if (nt < 6) { W = Wk; ldw = 192; n0 = (nt - 3) * 64; }
    else             { W = Wv; ldw = 768; n0 = (nt - 6) * 64; }
    gemm_mfma_body(H, W, out, mt * 64, n0, nt * 64, ldw, 1152);
}

// wo: y(1024x768) @ Wo(768x768) -> out(1024x768). grid (12,16)
__global__ __launch_bounds__(256) void gemm_wo_mfma(
    const float* __restrict__ Y, const float* __restrict__ Wo, float* __restrict__ out)
{
    const int nt = blockIdx.x, mt = blockIdx.y;
    gemm_mfma_body(Y, Wo, out, mt * 64, nt * 64, nt * 64, 768, 768);
}

// ---------------- per-chunk state (tiled): S[h][c] = phi(K_c)^T @ V_c (273x64), z = colsum phi ----------------
// grid (16, 12), block 256
__global__ __launch_bounds__(256) void chunk_state_k(
    const float* __restrict__ qkv, float* __restrict__ S, float* __restrict__ z)
{
    const int c = blockIdx.x, h = blockIdx.y;
    __shared__ float Kc[64][16];
    __shared__ float Vc[64][64];
    const int tid = threadIdx.x;
    {
        int s = tid >> 2, f4 = (tid & 3) * 4;
        *(float4*)&Kc[s][f4] = *(const float4*)&qkv[(size_t)(c * 64 + s) * 1152 + 192 + h * 16 + f4];
    }
    #pragma unroll
    for (int l = 0; l < 4; ++l) {
        int idx = tid + l * 256;
        int s = idx >> 4, d4 = (idx & 15) * 4;
        *(float4*)&Vc[s][d4] = *(const float4*)&qkv[(size_t)(c * 64 + s) * 1152 + 384 + h * 64 + d4];
    }
    __syncthreads();
    const int td = tid & 15, tg = tid >> 4;
    float acc[16][4] = {};
    float acce[4] = {}, acce2[4] = {};
    for (int s = 0; s < 64; ++s) {
        float kf = Kc[s][tg];
        float4 vv = *(const float4*)&Vc[s][td * 4];
        float4 k0 = *(const float4*)&Kc[s][0];
        float4 k1 = *(const float4*)&Kc[s][4];
        float4 k2 = *(const float4*)&Kc[s][8];
        float4 k3 = *(const float4*)&Kc[s][12];
        float kv[16] = {k0.x,k0.y,k0.z,k0.w, k1.x,k1.y,k1.z,k1.w,
                        k2.x,k2.y,k2.z,k2.w, k3.x,k3.y,k3.z,k3.w};
        float kprev = (tg == 0) ? 0.f : kv[tg - 1];
        float ev  = (tg == 0) ? 1.0f : kprev * 0.5f;   // phi row n = tg
        float ev2 = kv[15] * 0.5f;                      // phi row n = 16
        acce[0]  += ev  * vv.x; acce[1]  += ev  * vv.y; acce[2]  += ev  * vv.z; acce[3]  += ev  * vv.w;
        acce2[0] += ev2 * vv.x; acce2[1] += ev2 * vv.y; acce2[2] += ev2 * vv.z; acce2[3] += ev2 * vv.w;
        #pragma unroll
        for (int j = 0; j < 16; ++j) {
            float w = kf * kv[j] * C2;  // phi row n = 17 + tg*16 + j
            acc[j][0] += w * vv.x; acc[j][1] += w * vv.y;
            acc[j][2] += w * vv.z; acc[j][3] += w * vv.w;
        }
    }
    float* Sb = S + (size_t)((h * 16 + c) * 273) * 64;
    #pragma unroll
    for (int j = 0; j < 16; ++j) {
        float4 v = make_float4(acc[j][0], acc[j][1], acc[j][2], acc[j][3]);
        *(float4*)&Sb[(17 + tg * 16 + j) * 64 + td * 4] = v;
    }
    {
        float4 v = make_float4(acce[0], acce[1], acce[2], acce[3]);
        *(float4*)&Sb[tg * 64 + td * 4] = v;   // rows 0..15
    }
    if (tg == 15) {
        float4 v = make_float4(acce2[0], acce2[1], acce2[2], acce2[3]);
        *(float4*)&Sb[16 * 64 + td * 4] = v;   // row 16
    }
    float* zb = z + (h * 16 + c) * 273;
    for (int n = tid; n < 273; n += 256) {
        float zv = 0.f;
        if (n == 0) zv = 64.0f;
        else if (n < 17) { for (int s = 0; s < 64; ++s) zv += Kc[s][n - 1]; zv *= 0.5f; }
        else {
            int m = n - 17, f1 = m >> 4, f2 = m & 15;
            for (int s = 0; s < 64; ++s) zv += Kc[s][f1] * Kc[s][f2];
            zv *= C2;
        }
        zb[n] = zv;
    }
}

// ---------------- exclusive prefix over 16 chunks (in place) ----------------
__global__ __launch_bounds__(256) void scan_state_k(float* __restrict__ S, float* __restrict__ z)
{
    const int NS = 12 * 273 * 64;
    int e = blockIdx.x * 256 + threadIdx.x;
    if (e < NS) {
        int hh = e / (273 * 64), rem = e % (273 * 64);
        float* p = S + (size_t)hh * 16 * 273 * 64 + rem;
        float run = 0.f;
        #pragma unroll
        for (int c = 0; c < 16; ++c) { float v = p[c * 273 * 64]; p[c * 273 * 64] = run; run += v; }
    } else if (e < NS + 12 * 273) {
        int e2 = e - NS, hh = e2 / 273, n = e2 % 273;
        float* p = z + hh * 16 * 273 + n;
        float run = 0.f;
        #pragma unroll
        for (int c = 0; c < 16; ++c) { float v = p[c * 273]; p[c * 273] = run; run += v; }
    }
}

// ---------------- per-chunk output (tiled): intra (poly causal) + inter (phi(Q)@S_prefix) ----------------
// grid (16, 12), block 256
__global__ __launch_bounds__(256) void chunk_out_k(
    const float* __restrict__ qkv, const float* __restrict__ S, const float* __restrict__ z,
    float* __restrict__ y)
{
    const int c = blockIdx.x, h = blockIdx.y;
    __shared__ float Qc[64][17];
    __shared__ float Kc[64][17];
    __shared__ float Vc[64][64];
    __shared__ float Al[64][65];
    __shared__ float St[64][64];
    __shared__ float zl[273];
    __shared__ float dpart[4][64];
    __shared__ float denl[64];
    const int tid = threadIdx.x;
    {
        int s = tid >> 2, f4 = (tid & 3) * 4;
        float4 qv = *(const float4*)&qkv[(size_t)(c * 64 + s) * 1152 + h * 16 + f4];
        Qc[s][f4] = qv.x; Qc[s][f4 + 1] = qv.y; Qc[s][f4 + 2] = qv.z; Qc[s][f4 + 3] = qv.w;
        float4 kv = *(const float4*)&qkv[(size_t)(c * 64 + s) * 1152 + 192 + h * 16 + f4];
        Kc[s][f4] = kv.x; Kc[s][f4 + 1] = kv.y; Kc[s][f4 + 2] = kv.z; Kc[s][f4 + 3] = kv.w;
    }
    #pragma unroll
    for (int l = 0; l < 4; ++l) {
        int idx = tid + l * 256;
        int s = idx >> 4, d4 = (idx & 15) * 4;
        *(float4*)&Vc[s][d4] = *(const float4*)&qkv[(size_t)(c * 64 + s) * 1152 + 384 + h * 64 + d4];
    }
    const float* zb = z + (h * 16 + c) * 273;
    for (int n = tid; n < 273; n += 256) zl[n] = zb[n];
    __syncthreads();

    const int tj = tid & 15, ti = tid >> 4;
    float qreg[4][16];
    #pragma unroll
    for (int ii = 0; ii < 4; ++ii)
        #pragma unroll
        for (int f = 0; f < 16; ++f) qreg[ii][f] = Qc[ti * 4 + ii][f];

    {
        float a[4][4] = {};
        #pragma unroll
        for (int f = 0; f < 16; ++f) {
            float kb[4];
            #pragma unroll
            for (int jj = 0; jj < 4; ++jj) kb[jj] = Kc[tj * 4 + jj][f];
            #pragma unroll
            for (int ii = 0; ii < 4; ++ii)
                #pragma unroll
                for (int jj = 0; jj < 4; ++jj) a[ii][jj] += qreg[ii][f] * kb[jj];
        }
        #pragma unroll
        for (int ii = 0; ii < 4; ++ii)
            #pragma unroll
            for (int jj = 0; jj < 4; ++jj) {
                int i = ti * 4 + ii, j = tj * 4 + jj;
                float av = a[ii][jj];
                float sc = 1.f + 0.25f * av + av * av * (1.f / 32.f);
                Al[i][j] = (j <= i) ? sc : 0.f;
            }
    }
    __syncthreads();

    {
        int i = tid & 63, p = tid >> 6;
        int ns = (p * 273) >> 2, ne = ((p + 1) * 273) >> 2;
        float dp = 0.f;
        for (int n = ns; n < ne; ++n) {
            float ph;
            if (n == 0) ph = 1.f;
            else if (n < 17) ph = Qc[i][n - 1] * 0.5f;
            else { int m = n - 17; ph = Qc[i][m >> 4] * Qc[i][m & 15] * C2; }
            dp += ph * zl[n];
        }
        if (p == 0) { float di = 0.f; for (int j = 0; j < 64; ++j) di += Al[i][j]; dp += di; }
        dpart[p][i] = dp;
    }
    __syncthreads();
    if (tid < 64) denl[tid] = dpart[0][tid] + dpart[1][tid] + dpart[2][tid] + dpart[3][tid] + 1e-12f;

    float acc[4][4] = {};
    for (int j = 0; j < 64; ++j) {
        float4 vv = *(const float4*)&Vc[j][tj * 4];
        float aa[4];
        #pragma unroll
        for (int ii = 0; ii < 4; ++ii) aa[ii] = Al[ti * 4 + ii][j];
        #pragma unroll
        for (int ii = 0; ii < 4; ++ii) {
            acc[ii][0] += aa[ii] * vv.x; acc[ii][1] += aa[ii] * vv.y;
            acc[ii][2] += aa[ii] * vv.z; acc[ii][3] += aa[ii] * vv.w;
        }
    }
    const float* Sb = S + (size_t)((h * 16 + c) * 273) * 64;
    for (int idx = tid; idx < 17 * 64; idx += 256) St[idx >> 6][idx & 63] = Sb[idx];
    __syncthreads();
    #pragma unroll
    for (int n = 0; n < 17; ++n) {
        float4 sv = *(const float4*)&St[n][tj * 4];
        float w[4];
        #pragma unroll
        for (int ii = 0; ii < 4; ++ii) w[ii] = (n == 0) ? 1.f : qreg[ii][n - 1] * 0.5f;
        #pragma unroll
        for (int ii = 0; ii < 4; ++ii) {
            acc[ii][0] += w[ii] * sv.x; acc[ii][1] += w[ii] * sv.y;
            acc[ii][2] += w[ii] * sv.z; acc[ii][3] += w[ii] * sv.w;
        }
    }
    #pragma unroll
    for (int t = 0; t < 4; ++t) {
        __syncthreads();
        #pragma unroll
        for (int l = 0; l < 4; ++l) {
            int idx = tid + l * 256;
            int r = idx >> 4, d4 = (idx & 15) * 4;
            *(float4*)&St[r][d4] = *(const float4*)&Sb[(17 + t * 64 + r) * 64 + d4];
        }
        __syncthreads();
        #pragma unroll
        for (int b1 = 0; b1 < 4; ++b1) {
            int f1 = t * 4 + b1;
            float qf[4];
            #pragma unroll
            for (int ii = 0; ii < 4; ++ii) qf[ii] = qreg[ii][f1] * C2;
            #pragma unroll
            for (int f2 = 0; f2 < 16; ++f2) {
                int nn = b1 * 16 + f2;
                float4 sv = *(const float4*)&St[nn][tj * 4];
                float w[4];
                #pragma unroll
                for (int ii = 0; ii < 4; ++ii) w[ii] = qf[ii] * qreg[ii][f2];
                #pragma unroll
                for (int ii = 0; ii < 4; ++ii) {
                    acc[ii][0] += w[ii] * sv.x; acc[ii][1] += w[ii] * sv.y;
                    acc[ii][2] += w[ii] * sv.z; acc[ii][3] += w[ii] * sv.w;
                }
            }
        }
    }
    #pragma unroll
    for (int ii = 0; ii < 4; ++ii) {
        int i = ti * 4 + ii;
        float dn = denl[i];
        float4 o = make_float4(acc[ii][0] / dn, acc[ii][1] / dn, acc[ii][2] / dn, acc[ii][3] / dn);
        *(float4*)&y[(size_t)(c * 64 + i) * 768 + h * 64 + tj * 4] = o;
    }
}

extern "C" void kernel_launch(void* const* d_in, const int* in_sizes, int n_in,
                              void* d_out, int out_size, void* d_ws, size_t ws_size,
                              hipStream_t stream) {
    const float* hs = (const float*)d_in[0];
    const float* Wq = (const float*)d_in[1];
    const float* Wk = (const float*)d_in[2];
    const float* Wv = (const float*)d_in[3];
    const float* Wo = (const float*)d_in[4];
    float* out = (float*)d_out;
    float* ws  = (float*)d_ws;

    // Workspace layout (12*16*273*64 = 3,354,624 — do NOT change without re-deriving; rounds 1-2
    // failed solely because zb overlapped Sb).
    float* qkv = ws;                   // 1024*1152      = 1,179,648 floats
    float* yb  = ws + 1179648;         // 1024*768       =   786,432
    float* Sb  = ws + 1966080;         // 12*16*273*64   = 3,354,624
    float* zb  = ws + 5320704;         // 12*16*273      =    52,416
    // total 5,373,120 floats = 21.5 MB

    gemm_qkv_mfma<<<dim3(18, 16), 256, 0, stream>>>(hs, Wq, Wk, Wv, qkv);
    chunk_state_k<<<dim3(16, 12), 256, 0, stream>>>(qkv, Sb, zb);
    scan_state_k <<<832, 256, 0, stream>>>(Sb, zb);
    chunk_out_k  <<<dim3(16, 12), 256, 0, stream>>>(qkv, Sb, zb, yb);
    gemm_wo_mfma <<<dim3(12, 16), 256, 0, stream>>>(yb, Wo, out);
}

// Round 6
// 189.531 us; speedup vs baseline: 2.4088x; 1.0344x over previous
//
#include <hip/hip_runtime.h>

#define C2 0.17677669529663687f  // 1/(4*sqrt(2))

typedef __attribute__((ext_vector_type(8))) short short8;
typedef __attribute__((ext_vector_type(4))) float f32x4;

// fp32 -> bf16 round-to-nearest-even
__device__ __forceinline__ unsigned short f2bf(float x) {
    union { float f; unsigned u; } v; v.f = x;
    unsigned r = v.u + 0x7fffu + ((v.u >> 16) & 1u);
    return (unsigned short)(r >> 16);
}

// ---------------- MFMA GEMM body (64x64 block tile, 4 waves of 32x32, BK=32) ----------------
__device__ __forceinline__ void gemm_mfma_body(
    const float* __restrict__ A, const float* __restrict__ W,
    float* __restrict__ out, int row0, int n0, int outcol0, int ldw, int outld)
{
    __shared__ unsigned short Al[64][40];
    __shared__ unsigned short Bl[64][40];
    const int tid = threadIdx.x;
    const int lane = tid & 63;
    const int wave = tid >> 6;
    const int wm = wave & 1, wn = wave >> 1;
    const int quad = lane >> 4, lr = lane & 15;

    f32x4 acc[2][2] = {{{0.f,0.f,0.f,0.f},{0.f,0.f,0.f,0.f}},
                       {{0.f,0.f,0.f,0.f},{0.f,0.f,0.f,0.f}}};

    for (int k0 = 0; k0 < 768; k0 += 32) {
        #pragma unroll
        for (int l = 0; l < 2; ++l) {
            int idx = tid + l * 256;
            int r = idx >> 3, kq = (idx & 7) * 4;
            float4 a = *(const float4*)&A[(size_t)(row0 + r) * 768 + k0 + kq];
            ushort4 b = make_ushort4(f2bf(a.x), f2bf(a.y), f2bf(a.z), f2bf(a.w));
            *(ushort4*)&Al[r][kq] = b;
        }
        #pragma unroll
        for (int l = 0; l < 2; ++l) {
            int idx = tid + l * 256;
            int kr = idx >> 4, nq = (idx & 15) * 4;
            float4 b = *(const float4*)&W[(size_t)(k0 + kr) * ldw + n0 + nq];
            int col = ((((kr >> 3) ^ ((idx & 15) >> 2)) << 3)) | (kr & 7);
            Bl[nq + 0][col] = f2bf(b.x);
            Bl[nq + 1][col] = f2bf(b.y);
            Bl[nq + 2][col] = f2bf(b.z);
            Bl[nq + 3][col] = f2bf(b.w);
        }
        __syncthreads();
        short8 af[2], bfr[2];
        #pragma unroll
        for (int mi = 0; mi < 2; ++mi)
            af[mi] = *(const short8*)&Al[wm * 32 + mi * 16 + lr][quad << 3];
        #pragma unroll
        for (int ni = 0; ni < 2; ++ni) {
            int csw = quad ^ ((wn * 2 + ni) & 3);
            bfr[ni] = *(const short8*)&Bl[wn * 32 + ni * 16 + lr][csw << 3];
        }
        #pragma unroll
        for (int mi = 0; mi < 2; ++mi)
            #pragma unroll
            for (int ni = 0; ni < 2; ++ni)
                acc[mi][ni] = __builtin_amdgcn_mfma_f32_16x16x32_bf16(af[mi], bfr[ni], acc[mi][ni], 0, 0, 0);
        __syncthreads();
    }
    #pragma unroll
    for (int mi = 0; mi < 2; ++mi)
        #pragma unroll
        for (int ni = 0; ni < 2; ++ni)
            #pragma unroll
            for (int r = 0; r < 4; ++r)
                out[(size_t)(row0 + wm * 32 + mi * 16 + quad * 4 + r) * outld
                    + outcol0 + wn * 32 + ni * 16 + lr] = acc[mi][ni][r];
}

__global__ __launch_bounds__(256) void gemm_qkv_mfma(
    const float* __restrict__ H, const float* __restrict__ Wq,
    const float* __restrict__ Wk, const float* __restrict__ Wv,
    float* __restrict__ out)
{
    const int nt = blockIdx.x, mt = blockIdx.y;
    const float* W; int ldw, n0;
    if (nt < 3)      { W = Wq; ldw = 192; n0 = nt * 64; }
    else if (nt < 6) { W = Wk; ldw = 192; n0 = (nt - 3) * 64; }
    else             { W = Wv; ldw = 768; n0 = (nt - 6) * 64; }
    gemm_mfma_body(H, W, out, mt * 64, n0, nt * 64, ldw, 1152);
}

__global__ __launch_bounds__(256) void gemm_wo_mfma(
    const float* __restrict__ Y, const float* __restrict__ Wo, float* __restrict__ out)
{
    const int nt = blockIdx.x, mt = blockIdx.y;
    gemm_mfma_body(Y, Wo, out, mt * 64, nt * 64, nt * 64, 768, 768);
}

// ---------------- per-chunk state via MFMA: S[n<273][d] = sum_s phi_n(k_s) v_s[d]; z folded as d=64 ones-col ----
// grid (16, 12), block 256. A = phiK^T [320pad x 64s] bf16, B = [V^T | ones] [80 x 64s] bf16.
__global__ __launch_bounds__(256) void chunk_state_k(
    const float* __restrict__ qkv, float* __restrict__ S, float* __restrict__ z)
{
    const int c = blockIdx.x, h = blockIdx.y;
    __shared__ float Kc[64][17];
    __shared__ unsigned short Pk[320][72];   // [n-feat][s]  stride 144B: frag reads 2-way (free)
    __shared__ unsigned short Vt[80][72];    // [d][s], row 64 = ones (z), 65..79 zero
    const int tid = threadIdx.x;
    const int lane = tid & 63, wave = tid >> 6;
    const int quad = lane >> 4, lr = lane & 15;

    {
        int s = tid >> 2, f4 = (tid & 3) * 4;
        float4 kv = *(const float4*)&qkv[(size_t)(c * 64 + s) * 1152 + 192 + h * 16 + f4];
        Kc[s][f4 + 0] = kv.x; Kc[s][f4 + 1] = kv.y; Kc[s][f4 + 2] = kv.z; Kc[s][f4 + 3] = kv.w;
    }
    #pragma unroll
    for (int l = 0; l < 4; ++l) {
        int idx = tid + l * 256;
        int s = idx >> 4, d4 = (idx & 15) * 4;
        float4 vv = *(const float4*)&qkv[(size_t)(c * 64 + s) * 1152 + 384 + h * 64 + d4];
        Vt[d4 + 0][s] = f2bf(vv.x);
        Vt[d4 + 1][s] = f2bf(vv.y);
        Vt[d4 + 2][s] = f2bf(vv.z);
        Vt[d4 + 3][s] = f2bf(vv.w);
    }
    for (int idx = tid; idx < 16 * 72; idx += 256) {
        int rr = 64 + idx / 72, ss = idx % 72;
        Vt[rr][ss] = (rr == 64 && ss < 64) ? (unsigned short)0x3F80 : (unsigned short)0;
    }
    __syncthreads();
    // build Pk[n][s] = bf16(phi_n(k_s)); zero outside valid range (incl. m-pad rows)
    for (int idx = tid; idx < 2880; idx += 256) {   // 320 rows * 9 chunks of 8
        int n = idx / 9, s8 = (idx % 9) * 8;
        short8 v8;
        #pragma unroll
        for (int t = 0; t < 8; ++t) {
            int s = s8 + t;
            float ph = 0.f;
            if (s < 64 && n < 273) {
                if (n == 0) ph = 1.f;
                else if (n < 17) ph = Kc[s][n - 1] * 0.5f;
                else { int m = n - 17; ph = Kc[s][m >> 4] * Kc[s][m & 15] * C2; }
            }
            v8[t] = (short)f2bf(ph);
        }
        *(short8*)&Pk[n][s8] = v8;
    }
    __syncthreads();

    f32x4 acc[5][5];
    #pragma unroll
    for (int a = 0; a < 5; ++a)
        #pragma unroll
        for (int b = 0; b < 5; ++b) acc[a][b] = (f32x4){0.f, 0.f, 0.f, 0.f};
    #pragma unroll
    for (int ks = 0; ks < 2; ++ks) {
        short8 af[5], bfr[5];
        #pragma unroll
        for (int mt = 0; mt < 5; ++mt)
            af[mt] = *(const short8*)&Pk[(wave * 5 + mt) * 16 + lr][ks * 32 + quad * 8];
        #pragma unroll
        for (int nt = 0; nt < 5; ++nt)
            bfr[nt] = *(const short8*)&Vt[nt * 16 + lr][ks * 32 + quad * 8];
        #pragma unroll
        for (int mt = 0; mt < 5; ++mt)
            #pragma unroll
            for (int nt = 0; nt < 5; ++nt)
                acc[mt][nt] = __builtin_amdgcn_mfma_f32_16x16x32_bf16(af[mt], bfr[nt], acc[mt][nt], 0, 0, 0);
    }
    float* Sb = S + (size_t)((h * 16 + c) * 273) * 64;
    float* zb = z + (h * 16 + c) * 273;
    #pragma unroll
    for (int mt = 0; mt < 5; ++mt) {
        int m0 = (wave * 5 + mt) * 16 + quad * 4;
        #pragma unroll
        for (int r = 0; r < 4; ++r) {
            int n = m0 + r;
            if (n < 273) {
                #pragma unroll
                for (int nt = 0; nt < 4; ++nt)
                    Sb[(size_t)n * 64 + nt * 16 + lr] = acc[mt][nt][r];
                if (lr == 0) zb[n] = acc[mt][4][r];
            }
        }
    }
}

// ---------------- exclusive prefix over 16 chunks (in place) ----------------
__global__ __launch_bounds__(256) void scan_state_k(float* __restrict__ S, float* __restrict__ z)
{
    const int NS = 12 * 273 * 64;
    int e = blockIdx.x * 256 + threadIdx.x;
    if (e < NS) {
        int hh = e / (273 * 64), rem = e % (273 * 64);
        float* p = S + (size_t)hh * 16 * 273 * 64 + rem;
        float run = 0.f;
        #pragma unroll
        for (int c = 0; c < 16; ++c) { float v = p[c * 273 * 64]; p[c * 273 * 64] = run; run += v; }
    } else if (e < NS + 12 * 273) {
        int e2 = e - NS, hh = e2 / 273, n = e2 % 273;
        float* p = z + hh * 16 * 273 + n;
        float run = 0.f;
        #pragma unroll
        for (int c = 0; c < 16; ++c) { float v = p[c * 273]; p[c * 273] = run; run += v; }
    }
}

// ---------------- per-chunk output via ONE fused MFMA GEMM ----------------
// num[64x64] = [phiQ(273,pad288) | scores(64)] [64x352] @ [S^T | V^T] [64x352]^T-frag
// den = phiQ.z (fused in build) + rowsum(scores) (in-register shfl) + eps
// grid (16, 12), block 256
__global__ __launch_bounds__(256) void chunk_out_k(
    const float* __restrict__ qkv, const float* __restrict__ S, const float* __restrict__ z,
    float* __restrict__ y)
{
    const int c = blockIdx.x, h = blockIdx.y;
    __shared__ float Qc[64][17];
    __shared__ unsigned short Aq[64][40];    // Q bf16, k 16..31 zero (QK^T A-op)
    __shared__ unsigned short Kb[64][40];    // K bf16 [j][f]   (QK^T B-op)
    __shared__ unsigned short Pq[64][360];   // [i][k]: 0..272 phiQ, 273..287 zero, 288..351 scores
    __shared__ unsigned short Sv[64][360];   // [d][k]: 0..272 S^T, 273..287 zero, 288..351 V^T
    __shared__ float zl[288];
    __shared__ float dpart[6][64];           // 0..3 z-part (per wave col-range), 4..5 rowsum (per wn)
    const int tid = threadIdx.x;
    const int lane = tid & 63, wave = tid >> 6;
    const int wm = wave & 1, wn = wave >> 1;
    const int quad = lane >> 4, lr = lane & 15;

    // ---- stage ----
    {
        int s = tid >> 2, f4 = (tid & 3) * 4;
        const float* base = &qkv[(size_t)(c * 64 + s) * 1152 + h * 16];
        float4 qv = *(const float4*)&base[f4];
        float4 kv = *(const float4*)&base[192 + f4];
        Qc[s][f4 + 0] = qv.x; Qc[s][f4 + 1] = qv.y; Qc[s][f4 + 2] = qv.z; Qc[s][f4 + 3] = qv.w;
        *(ushort4*)&Aq[s][f4] = make_ushort4(f2bf(qv.x), f2bf(qv.y), f2bf(qv.z), f2bf(qv.w));
        *(ushort4*)&Kb[s][f4] = make_ushort4(f2bf(kv.x), f2bf(kv.y), f2bf(kv.z), f2bf(kv.w));
        *(ushort4*)&Aq[s][16 + (tid & 3) * 4] = make_ushort4(0, 0, 0, 0);
        *(ushort4*)&Kb[s][16 + (tid & 3) * 4] = make_ushort4(0, 0, 0, 0);
    }
    #pragma unroll
    for (int l = 0; l < 4; ++l) {                    // V -> Sv cols 288..351
        int idx = tid + l * 256;
        int s = idx >> 4, d4 = (idx & 15) * 4;
        float4 vv = *(const float4*)&qkv[(size_t)(c * 64 + s) * 1152 + 384 + h * 64 + d4];
        Sv[d4 + 0][288 + s] = f2bf(vv.x);
        Sv[d4 + 1][288 + s] = f2bf(vv.y);
        Sv[d4 + 2][288 + s] = f2bf(vv.z);
        Sv[d4 + 3][288 + s] = f2bf(vv.w);
    }
    const float* Sg = S + (size_t)((h * 16 + c) * 273) * 64;
    for (int idx = tid; idx < 4368; idx += 256) {    // S^T -> Sv cols 0..272
        int n = idx >> 4, d4 = (idx & 15) * 4;
        float4 sv = *(const float4*)&Sg[(size_t)n * 64 + d4];
        Sv[d4 + 0][n] = f2bf(sv.x);
        Sv[d4 + 1][n] = f2bf(sv.y);
        Sv[d4 + 2][n] = f2bf(sv.z);
        Sv[d4 + 3][n] = f2bf(sv.w);
    }
    for (int idx = tid; idx < 64 * 16; idx += 256) { // zero Sv cols 273..287
        int d = idx >> 4, n = 273 + (idx & 15);
        if (n < 288) Sv[d][n] = 0;
    }
    const float* zg = z + (h * 16 + c) * 273;
    for (int idx = tid; idx < 288; idx += 256) zl[idx] = (idx < 273) ? zg[idx] : 0.f;
    __syncthreads();

    // ---- QK^T via MFMA (k=16 data + 16 zero-pad) ----
    f32x4 accS[2][2] = {{{0.f,0.f,0.f,0.f},{0.f,0.f,0.f,0.f}},
                        {{0.f,0.f,0.f,0.f},{0.f,0.f,0.f,0.f}}};
    {
        short8 af[2], bfr[2];
        #pragma unroll
        for (int mi = 0; mi < 2; ++mi)
            af[mi] = *(const short8*)&Aq[wm * 32 + mi * 16 + lr][quad * 8];
        #pragma unroll
        for (int ni = 0; ni < 2; ++ni)
            bfr[ni] = *(const short8*)&Kb[wn * 32 + ni * 16 + lr][quad * 8];
        #pragma unroll
        for (int mi = 0; mi < 2; ++mi)
            #pragma unroll
            for (int ni = 0; ni < 2; ++ni)
                accS[mi][ni] = __builtin_amdgcn_mfma_f32_16x16x32_bf16(af[mi], bfr[ni], accS[mi][ni], 0, 0, 0);
    }

    // ---- phiQ build + z-part of denominator (wave w covers cols w*72..w*72+71; n wave-uniform) ----
    {
        int i = lane;
        float qr[16];
        #pragma unroll
        for (int f = 0; f < 16; ++f) qr[f] = Qc[i][f];
        float dp = 0.f;
        int n0 = wave * 72;
        for (int n = n0; n < n0 + 72; ++n) {
            float ph;
            if (n == 0) ph = 1.f;
            else if (n < 17) ph = qr[n - 1] * 0.5f;
            else if (n < 273) { int m = n - 17; ph = qr[m >> 4] * qr[m & 15] * C2; }
            else ph = 0.f;
            Pq[i][n] = f2bf(ph);
            dp += ph * zl[n];
        }
        dpart[wave][i] = dp;
    }

    // ---- scores: poly + causal mask on C-frags; rowsum in-register; write bf16 to Pq cols 288+ ----
    #pragma unroll
    for (int mi = 0; mi < 2; ++mi) {
        float rs[4] = {0.f, 0.f, 0.f, 0.f};
        #pragma unroll
        for (int ni = 0; ni < 2; ++ni)
            #pragma unroll
            for (int r = 0; r < 4; ++r) {
                int i = wm * 32 + mi * 16 + quad * 4 + r;
                int j = wn * 32 + ni * 16 + lr;
                float u = accS[mi][ni][r];
                float sc = (j <= i) ? (1.f + 0.25f * u + u * u * (1.f / 32.f)) : 0.f;
                rs[r] += sc;
                Pq[i][288 + j] = f2bf(sc);
            }
        #pragma unroll
        for (int r = 0; r < 4; ++r) {
            float v = rs[r];
            v += __shfl_xor(v, 1);
            v += __shfl_xor(v, 2);
            v += __shfl_xor(v, 4);
            v += __shfl_xor(v, 8);
            if (lr == 0) dpart[4 + wn][wm * 32 + mi * 16 + quad * 4 + r] = v;
        }
    }
    __syncthreads();

    // ---- fused main MFMA: K = 352 (11 ksteps) ----
    f32x4 acc[2][2] = {{{0.f,0.f,0.f,0.f},{0.f,0.f,0.f,0.f}},
                       {{0.f,0.f,0.f,0.f},{0.f,0.f,0.f,0.f}}};
    #pragma unroll
    for (int ks = 0; ks < 11; ++ks) {
        short8 af[2], bfr[2];
        #pragma unroll
        for (int mi = 0; mi < 2; ++mi)
            af[mi] = *(const short8*)&Pq[wm * 32 + mi * 16 + lr][ks * 32 + quad * 8];
        #pragma unroll
        for (int ni = 0; ni < 2; ++ni)
            bfr[ni] = *(const short8*)&Sv[wn * 32 + ni * 16 + lr][ks * 32 + quad * 8];
        #pragma unroll
        for (int mi = 0; mi < 2; ++mi)
            #pragma unroll
            for (int ni = 0; ni < 2; ++ni)
                acc[mi][ni] = __builtin_amdgcn_mfma_f32_16x16x32_bf16(af[mi], bfr[ni], acc[mi][ni], 0, 0, 0);
    }

    // ---- final: divide by den, store ----
    #pragma unroll
    for (int mi = 0; mi < 2; ++mi)
        #pragma unroll
        for (int r = 0; r < 4; ++r) {
            int i = wm * 32 + mi * 16 + quad * 4 + r;
            float den = dpart[0][i] + dpart[1][i] + dpart[2][i] +
                        dpart[3][i] + dpart[4][i] + dpart[5][i] + 1e-12f;
            float rden = 1.f / den;
            #pragma unroll
            for (int ni = 0; ni < 2; ++ni)
                y[(size_t)(c * 64 + i) * 768 + h * 64 + wn * 32 + ni * 16 + lr] = acc[mi][ni][r] * rden;
        }
}

extern "C" void kernel_launch(void* const* d_in, const int* in_sizes, int n_in,
                              void* d_out, int out_size, void* d_ws, size_t ws_size,
                              hipStream_t stream) {
    const float* hs = (const float*)d_in[0];
    const float* Wq = (const float*)d_in[1];
    const float* Wk = (const float*)d_in[2];
    const float* Wv = (const float*)d_in[3];
    const float* Wo = (const float*)d_in[4];
    float* out = (float*)d_out;
    float* ws  = (float*)d_ws;

    // Workspace layout (12*16*273*64 = 3,354,624 — do NOT change without re-deriving).
    float* qkv = ws;                   // 1024*1152      = 1,179,648 floats
    float* yb  = ws + 1179648;         // 1024*768       =   786,432
    float* Sb  = ws + 1966080;         // 12*16*273*64   = 3,354,624
    float* zb  = ws + 5320704;         // 12*16*273      =    52,416

    gemm_qkv_mfma<<<dim3(18, 16), 256, 0, stream>>>(hs, Wq, Wk, Wv, qkv);
    chunk_state_k<<<dim3(16, 12), 256, 0, stream>>>(qkv, Sb, zb);
    scan_state_k <<<832, 256, 0, stream>>>(Sb, zb);
    chunk_out_k  <<<dim3(16, 12), 256, 0, stream>>>(qkv, Sb, zb, yb);
    gemm_wo_mfma <<<dim3(12, 16), 256, 0, stream>>>(yb, Wo, out);
}

// Round 7
// 154.031 us; speedup vs baseline: 2.9639x; 1.2305x over previous
//
#include <hip/hip_runtime.h>

#define C2 0.17677669529663687f  // 1/(4*sqrt(2))

typedef __attribute__((ext_vector_type(8))) short short8;
typedef __attribute__((ext_vector_type(4))) float f32x4;

// fp32 -> bf16 round-to-nearest-even
__device__ __forceinline__ unsigned short f2bf(float x) {
    union { float f; unsigned u; } v; v.f = x;
    unsigned r = v.u + 0x7fffu + ((v.u >> 16) & 1u);
    return (unsigned short)(r >> 16);
}

// ---------------- split-K MFMA GEMM (64x64 tile, 4 waves of 32x32, BK=32, K-slice=256) ----------------
// Register-prefetch double-buffered LDS, ONE barrier per K-step.
// Hazard proof: iter i reads buf[i&1], writes buf[(i+1)&1]; reads of buf[(i+1)&1] happened in
// iter i-1 and completed before barrier i-1. fp32 partials combined via unsafeAtomicAdd
// (native global_atomic_add_f32; out zeroed via hipMemsetAsync before launch).
__device__ __forceinline__ void gemm_mfma_splitk_body(
    const float* __restrict__ A, const float* __restrict__ W,
    float* __restrict__ out, int row0, int n0, int outcol0, int ldw, int outld, int k0base)
{
    __shared__ unsigned short Al[2][64][40];
    __shared__ unsigned short Bl[2][64][40];
    const int tid = threadIdx.x;
    const int lane = tid & 63, wave = tid >> 6;
    const int wm = wave & 1, wn = wave >> 1;
    const int quad = lane >> 4, lr = lane & 15;

    f32x4 acc[2][2] = {{{0.f,0.f,0.f,0.f},{0.f,0.f,0.f,0.f}},
                       {{0.f,0.f,0.f,0.f},{0.f,0.f,0.f,0.f}}};

    // staging indices (per l = 0,1): A: r=idx>>3, kq=(idx&7)*4 ; B: kr=idx>>4, nq=(idx&15)*4
    float4 ra[2], rb[2];
    #pragma unroll
    for (int l = 0; l < 2; ++l) {
        int idx = tid + l * 256;
        ra[l] = *(const float4*)&A[(size_t)(row0 + (idx >> 3)) * 768 + k0base + (idx & 7) * 4];
        rb[l] = *(const float4*)&W[(size_t)(k0base + (idx >> 4)) * ldw + n0 + (idx & 15) * 4];
    }
    #pragma unroll
    for (int l = 0; l < 2; ++l) {
        int idx = tid + l * 256;
        *(ushort4*)&Al[0][idx >> 3][(idx & 7) * 4] =
            make_ushort4(f2bf(ra[l].x), f2bf(ra[l].y), f2bf(ra[l].z), f2bf(ra[l].w));
        int kr = idx >> 4, nq = (idx & 15) * 4;
        int col = (((kr >> 3) ^ ((idx & 15) >> 2)) << 3) | (kr & 7);
        Bl[0][nq + 0][col] = f2bf(rb[l].x);
        Bl[0][nq + 1][col] = f2bf(rb[l].y);
        Bl[0][nq + 2][col] = f2bf(rb[l].z);
        Bl[0][nq + 3][col] = f2bf(rb[l].w);
    }
    __syncthreads();

    const int ITER = 8;   // 256 / 32
    #pragma unroll
    for (int i = 0; i < ITER; ++i) {
        const int cur = i & 1, nxt = cur ^ 1;
        float4 na[2], nb[2];
        if (i + 1 < ITER) {
            int kn = k0base + (i + 1) * 32;
            #pragma unroll
            for (int l = 0; l < 2; ++l) {
                int idx = tid + l * 256;
                na[l] = *(const float4*)&A[(size_t)(row0 + (idx >> 3)) * 768 + kn + (idx & 7) * 4];
                nb[l] = *(const float4*)&W[(size_t)(kn + (idx >> 4)) * ldw + n0 + (idx & 15) * 4];
            }
        }
        short8 af[2], bfr[2];
        #pragma unroll
        for (int mi = 0; mi < 2; ++mi)
            af[mi] = *(const short8*)&Al[cur][wm * 32 + mi * 16 + lr][quad << 3];
        #pragma unroll
        for (int ni = 0; ni < 2; ++ni) {
            int csw = quad ^ ((wn * 2 + ni) & 3);
            bfr[ni] = *(const short8*)&Bl[cur][wn * 32 + ni * 16 + lr][csw << 3];
        }
        #pragma unroll
        for (int mi = 0; mi < 2; ++mi)
            #pragma unroll
            for (int ni = 0; ni < 2; ++ni)
                acc[mi][ni] = __builtin_amdgcn_mfma_f32_16x16x32_bf16(af[mi], bfr[ni], acc[mi][ni], 0, 0, 0);
        if (i + 1 < ITER) {
            #pragma unroll
            for (int l = 0; l < 2; ++l) {
                int idx = tid + l * 256;
                *(ushort4*)&Al[nxt][idx >> 3][(idx & 7) * 4] =
                    make_ushort4(f2bf(na[l].x), f2bf(na[l].y), f2bf(na[l].z), f2bf(na[l].w));
                int kr = idx >> 4, nq = (idx & 15) * 4;
                int col = (((kr >> 3) ^ ((idx & 15) >> 2)) << 3) | (kr & 7);
                Bl[nxt][nq + 0][col] = f2bf(nb[l].x);
                Bl[nxt][nq + 1][col] = f2bf(nb[l].y);
                Bl[nxt][nq + 2][col] = f2bf(nb[l].z);
                Bl[nxt][nq + 3][col] = f2bf(nb[l].w);
            }
        }
        __syncthreads();
    }
    #pragma unroll
    for (int mi = 0; mi < 2; ++mi)
        #pragma unroll
        for (int ni = 0; ni < 2; ++ni)
            #pragma unroll
            for (int r = 0; r < 4; ++r)
                unsafeAtomicAdd(&out[(size_t)(row0 + wm * 32 + mi * 16 + quad * 4 + r) * outld
                                     + outcol0 + wn * 32 + ni * 16 + lr], acc[mi][ni][r]);
}

// qkv: hidden(1024x768) @ [Wq|Wk|Wv] -> qkv(1024x1152). grid (18,16,3)
__global__ __launch_bounds__(256) void gemm_qkv_mfma(
    const float* __restrict__ H, const float* __restrict__ Wq,
    const float* __restrict__ Wk, const float* __restrict__ Wv,
    float* __restrict__ out)
{
    const int nt = blockIdx.x, mt = blockIdx.y, sk = blockIdx.z;
    const float* W; int ldw, n0;
    if (nt < 3)      { W = Wq; ldw = 192; n0 = nt * 64; }
    else if (nt < 6) { W = Wk; ldw = 192; n0 = (nt - 3) * 64; }
    else             { W = Wv; ldw = 768; n0 = (nt - 6) * 64; }
    gemm_mfma_splitk_body(H, W, out, mt * 64, n0, nt * 64, ldw, 1152, sk * 256);
}

// wo: y(1024x768) @ Wo(768x768) -> out(1024x768). grid (12,16,3)
__global__ __launch_bounds__(256) void gemm_wo_mfma(
    const float* __restrict__ Y, const float* __restrict__ Wo, float* __restrict__ out)
{
    const int nt = blockIdx.x, mt = blockIdx.y, sk = blockIdx.z;
    gemm_mfma_splitk_body(Y, Wo, out, mt * 64, nt * 64, nt * 64, 768, 768, sk * 256);
}

// ---------------- per-chunk state via MFMA: S[n<273][d] = sum_s phi_n(k_s) v_s[d]; z folded as d=64 ones-col ----
// grid (16, 12), block 256. A = phiK^T [320pad x 64s] bf16, B = [V^T | ones] [80 x 64s] bf16.
__global__ __launch_bounds__(256) void chunk_state_k(
    const float* __restrict__ qkv, float* __restrict__ S, float* __restrict__ z)
{
    const int c = blockIdx.x, h = blockIdx.y;
    __shared__ float Kc[64][17];
    __shared__ unsigned short Pk[320][72];
    __shared__ unsigned short Vt[80][72];
    const int tid = threadIdx.x;
    const int lane = tid & 63, wave = tid >> 6;
    const int quad = lane >> 4, lr = lane & 15;

    {
        int s = tid >> 2, f4 = (tid & 3) * 4;
        float4 kv = *(const float4*)&qkv[(size_t)(c * 64 + s) * 1152 + 192 + h * 16 + f4];
        Kc[s][f4 + 0] = kv.x; Kc[s][f4 + 1] = kv.y; Kc[s][f4 + 2] = kv.z; Kc[s][f4 + 3] = kv.w;
    }
    #pragma unroll
    for (int l = 0; l < 4; ++l) {
        int idx = tid + l * 256;
        int s = idx >> 4, d4 = (idx & 15) * 4;
        float4 vv = *(const float4*)&qkv[(size_t)(c * 64 + s) * 1152 + 384 + h * 64 + d4];
        Vt[d4 + 0][s] = f2bf(vv.x);
        Vt[d4 + 1][s] = f2bf(vv.y);
        Vt[d4 + 2][s] = f2bf(vv.z);
        Vt[d4 + 3][s] = f2bf(vv.w);
    }
    for (int idx = tid; idx < 16 * 72; idx += 256) {
        int rr = 64 + idx / 72, ss = idx % 72;
        Vt[rr][ss] = (rr == 64 && ss < 64) ? (unsigned short)0x3F80 : (unsigned short)0;
    }
    __syncthreads();
    for (int idx = tid; idx < 2880; idx += 256) {
        int n = idx / 9, s8 = (idx % 9) * 8;
        short8 v8;
        #pragma unroll
        for (int t = 0; t < 8; ++t) {
            int s = s8 + t;
            float ph = 0.f;
            if (s < 64 && n < 273) {
                if (n == 0) ph = 1.f;
                else if (n < 17) ph = Kc[s][n - 1] * 0.5f;
                else { int m = n - 17; ph = Kc[s][m >> 4] * Kc[s][m & 15] * C2; }
            }
            v8[t] = (short)f2bf(ph);
        }
        *(short8*)&Pk[n][s8] = v8;
    }
    __syncthreads();

    f32x4 acc[5][5];
    #pragma unroll
    for (int a = 0; a < 5; ++a)
        #pragma unroll
        for (int b = 0; b < 5; ++b) acc[a][b] = (f32x4){0.f, 0.f, 0.f, 0.f};
    #pragma unroll
    for (int ks = 0; ks < 2; ++ks) {
        short8 af[5], bfr[5];
        #pragma unroll
        for (int mt = 0; mt < 5; ++mt)
            af[mt] = *(const short8*)&Pk[(wave * 5 + mt) * 16 + lr][ks * 32 + quad * 8];
        #pragma unroll
        for (int nt = 0; nt < 5; ++nt)
            bfr[nt] = *(const short8*)&Vt[nt * 16 + lr][ks * 32 + quad * 8];
        #pragma unroll
        for (int mt = 0; mt < 5; ++mt)
            #pragma unroll
            for (int nt = 0; nt < 5; ++nt)
                acc[mt][nt] = __builtin_amdgcn_mfma_f32_16x16x32_bf16(af[mt], bfr[nt], acc[mt][nt], 0, 0, 0);
    }
    float* Sb = S + (size_t)((h * 16 + c) * 273) * 64;
    float* zb = z + (h * 16 + c) * 273;
    #pragma unroll
    for (int mt = 0; mt < 5; ++mt) {
        int m0 = (wave * 5 + mt) * 16 + quad * 4;
        #pragma unroll
        for (int r = 0; r < 4; ++r) {
            int n = m0 + r;
            if (n < 273) {
                #pragma unroll
                for (int nt = 0; nt < 4; ++nt)
                    Sb[(size_t)n * 64 + nt * 16 + lr] = acc[mt][nt][r];
                if (lr == 0) zb[n] = acc[mt][4][r];
            }
        }
    }
}

// ---------------- exclusive prefix over 16 chunks (in place) ----------------
__global__ __launch_bounds__(256) void scan_state_k(float* __restrict__ S, float* __restrict__ z)
{
    const int NS = 12 * 273 * 64;
    int e = blockIdx.x * 256 + threadIdx.x;
    if (e < NS) {
        int hh = e / (273 * 64), rem = e % (273 * 64);
        float* p = S + (size_t)hh * 16 * 273 * 64 + rem;
        float run = 0.f;
        #pragma unroll
        for (int c = 0; c < 16; ++c) { float v = p[c * 273 * 64]; p[c * 273 * 64] = run; run += v; }
    } else if (e < NS + 12 * 273) {
        int e2 = e - NS, hh = e2 / 273, n = e2 % 273;
        float* p = z + hh * 16 * 273 + n;
        float run = 0.f;
        #pragma unroll
        for (int c = 0; c < 16; ++c) { float v = p[c * 273]; p[c * 273] = run; run += v; }
    }
}

// ---------------- per-chunk output via ONE fused MFMA GEMM ----------------
__global__ __launch_bounds__(256) void chunk_out_k(
    const float* __restrict__ qkv, const float* __restrict__ S, const float* __restrict__ z,
    float* __restrict__ y)
{
    const int c = blockIdx.x, h = blockIdx.y;
    __shared__ float Qc[64][17];
    __shared__ unsigned short Aq[64][40];
    __shared__ unsigned short Kb[64][40];
    __shared__ unsigned short Pq[64][360];
    __shared__ unsigned short Sv[64][360];
    __shared__ float zl[288];
    __shared__ float dpart[6][64];
    const int tid = threadIdx.x;
    const int lane = tid & 63, wave = tid >> 6;
    const int wm = wave & 1, wn = wave >> 1;
    const int quad = lane >> 4, lr = lane & 15;

    {
        int s = tid >> 2, f4 = (tid & 3) * 4;
        const float* base = &qkv[(size_t)(c * 64 + s) * 1152 + h * 16];
        float4 qv = *(const float4*)&base[f4];
        float4 kv = *(const float4*)&base[192 + f4];
        Qc[s][f4 + 0] = qv.x; Qc[s][f4 + 1] = qv.y; Qc[s][f4 + 2] = qv.z; Qc[s][f4 + 3] = qv.w;
        *(ushort4*)&Aq[s][f4] = make_ushort4(f2bf(qv.x), f2bf(qv.y), f2bf(qv.z), f2bf(qv.w));
        *(ushort4*)&Kb[s][f4] = make_ushort4(f2bf(kv.x), f2bf(kv.y), f2bf(kv.z), f2bf(kv.w));
        *(ushort4*)&Aq[s][16 + (tid & 3) * 4] = make_ushort4(0, 0, 0, 0);
        *(ushort4*)&Kb[s][16 + (tid & 3) * 4] = make_ushort4(0, 0, 0, 0);
    }
    #pragma unroll
    for (int l = 0; l < 4; ++l) {
        int idx = tid + l * 256;
        int s = idx >> 4, d4 = (idx & 15) * 4;
        float4 vv = *(const float4*)&qkv[(size_t)(c * 64 + s) * 1152 + 384 + h * 64 + d4];
        Sv[d4 + 0][288 + s] = f2bf(vv.x);
        Sv[d4 + 1][288 + s] = f2bf(vv.y);
        Sv[d4 + 2][288 + s] = f2bf(vv.z);
        Sv[d4 + 3][288 + s] = f2bf(vv.w);
    }
    const float* Sg = S + (size_t)((h * 16 + c) * 273) * 64;
    for (int idx = tid; idx < 4368; idx += 256) {
        int n = idx >> 4, d4 = (idx & 15) * 4;
        float4 sv = *(const float4*)&Sg[(size_t)n * 64 + d4];
        Sv[d4 + 0][n] = f2bf(sv.x);
        Sv[d4 + 1][n] = f2bf(sv.y);
        Sv[d4 + 2][n] = f2bf(sv.z);
        Sv[d4 + 3][n] = f2bf(sv.w);
    }
    for (int idx = tid; idx < 64 * 16; idx += 256) {
        int d = idx >> 4, n = 273 + (idx & 15);
        if (n < 288) Sv[d][n] = 0;
    }
    const float* zg = z + (h * 16 + c) * 273;
    for (int idx = tid; idx < 288; idx += 256) zl[idx] = (idx < 273) ? zg[idx] : 0.f;
    __syncthreads();

    f32x4 accS[2][2] = {{{0.f,0.f,0.f,0.f},{0.f,0.f,0.f,0.f}},
                        {{0.f,0.f,0.f,0.f},{0.f,0.f,0.f,0.f}}};
    {
        short8 af[2], bfr[2];
        #pragma unroll
        for (int mi = 0; mi < 2; ++mi)
            af[mi] = *(const short8*)&Aq[wm * 32 + mi * 16 + lr][quad * 8];
        #pragma unroll
        for (int ni = 0; ni < 2; ++ni)
            bfr[ni] = *(const short8*)&Kb[wn * 32 + ni * 16 + lr][quad * 8];
        #pragma unroll
        for (int mi = 0; mi < 2; ++mi)
            #pragma unroll
            for (int ni = 0; ni < 2; ++ni)
                accS[mi][ni] = __builtin_amdgcn_mfma_f32_16x16x32_bf16(af[mi], bfr[ni], accS[mi][ni], 0, 0, 0);
    }

    {
        int i = lane;
        float qr[16];
        #pragma unroll
        for (int f = 0; f < 16; ++f) qr[f] = Qc[i][f];
        float dp = 0.f;
        int n0 = wave * 72;
        for (int n = n0; n < n0 + 72; ++n) {
            float ph;
            if (n == 0) ph = 1.f;
            else if (n < 17) ph = qr[n - 1] * 0.5f;
            else if (n < 273) { int m = n - 17; ph = qr[m >> 4] * qr[m & 15] * C2; }
            else ph = 0.f;
            Pq[i][n] = f2bf(ph);
            dp += ph * zl[n];
        }
        dpart[wave][i] = dp;
    }

    #pragma unroll
    for (int mi = 0; mi < 2; ++mi) {
        float rs[4] = {0.f, 0.f, 0.f, 0.f};
        #pragma unroll
        for (int ni = 0; ni < 2; ++ni)
            #pragma unroll
            for (int r = 0; r < 4; ++r) {
                int i = wm * 32 + mi * 16 + quad * 4 + r;
                int j = wn * 32 + ni * 16 + lr;
                float u = accS[mi][ni][r];
                float sc = (j <= i) ? (1.f + 0.25f * u + u * u * (1.f / 32.f)) : 0.f;
                rs[r] += sc;
                Pq[i][288 + j] = f2bf(sc);
            }
        #pragma unroll
        for (int r = 0; r < 4; ++r) {
            float v = rs[r];
            v += __shfl_xor(v, 1);
            v += __shfl_xor(v, 2);
            v += __shfl_xor(v, 4);
            v += __shfl_xor(v, 8);
            if (lr == 0) dpart[4 + wn][wm * 32 + mi * 16 + quad * 4 + r] = v;
        }
    }
    __syncthreads();

    f32x4 acc[2][2] = {{{0.f,0.f,0.f,0.f},{0.f,0.f,0.f,0.f}},
                       {{0.f,0.f,0.f,0.f},{0.f,0.f,0.f,0.f}}};
    #pragma unroll
    for (int ks = 0; ks < 11; ++ks) {
        short8 af[2], bfr[2];
        #pragma unroll
        for (int mi = 0; mi < 2; ++mi)
            af[mi] = *(const short8*)&Pq[wm * 32 + mi * 16 + lr][ks * 32 + quad * 8];
        #pragma unroll
        for (int ni = 0; ni < 2; ++ni)
            bfr[ni] = *(const short8*)&Sv[wn * 32 + ni * 16 + lr][ks * 32 + quad * 8];
        #pragma unroll
        for (int mi = 0; mi < 2; ++mi)
            #pragma unroll
            for (int ni = 0; ni < 2; ++ni)
                acc[mi][ni] = __builtin_amdgcn_mfma_f32_16x16x32_bf16(af[mi], bfr[ni], acc[mi][ni], 0, 0, 0);
    }

    #pragma unroll
    for (int mi = 0; mi < 2; ++mi)
        #pragma unroll
        for (int r = 0; r < 4; ++r) {
            int i = wm * 32 + mi * 16 + quad * 4 + r;
            float den = dpart[0][i] + dpart[1][i] + dpart[2][i] +
                        dpart[3][i] + dpart[4][i] + dpart[5][i] + 1e-12f;
            float rden = 1.f / den;
            #pragma unroll
            for (int ni = 0; ni < 2; ++ni)
                y[(size_t)(c * 64 + i) * 768 + h * 64 + wn * 32 + ni * 16 + lr] = acc[mi][ni][r] * rden;
        }
}

extern "C" void kernel_launch(void* const* d_in, const int* in_sizes, int n_in,
                              void* d_out, int out_size, void* d_ws, size_t ws_size,
                              hipStream_t stream) {
    const float* hs = (const float*)d_in[0];
    const float* Wq = (const float*)d_in[1];
    const float* Wk = (const float*)d_in[2];
    const float* Wv = (const float*)d_in[3];
    const float* Wo = (const float*)d_in[4];
    float* out = (float*)d_out;
    float* ws  = (float*)d_ws;

    // Workspace layout (12*16*273*64 = 3,354,624 — do NOT change without re-deriving).
    float* qkv = ws;                   // 1024*1152      = 1,179,648 floats
    float* yb  = ws + 1179648;         // 1024*768       =   786,432
    float* Sb  = ws + 1966080;         // 12*16*273*64   = 3,354,624
    float* zb  = ws + 5320704;         // 12*16*273      =    52,416

    // split-K GEMMs accumulate with fp32 atomics -> zero the destinations first
    hipMemsetAsync(qkv, 0, (size_t)1179648 * sizeof(float), stream);
    hipMemsetAsync(out, 0, (size_t)out_size * sizeof(float), stream);

    gemm_qkv_mfma<<<dim3(18, 16, 3), 256, 0, stream>>>(hs, Wq, Wk, Wv, qkv);
    chunk_state_k<<<dim3(16, 12), 256, 0, stream>>>(qkv, Sb, zb);
    scan_state_k <<<832, 256, 0, stream>>>(Sb, zb);
    chunk_out_k  <<<dim3(16, 12), 256, 0, stream>>>(qkv, Sb, zb, yb);
    gemm_wo_mfma <<<dim3(12, 16, 3), 256, 0, stream>>>(yb, Wo, out);
}

// Round 8
// 137.190 us; speedup vs baseline: 3.3277x; 1.1228x over previous
//
#include <hip/hip_runtime.h>

#define C2 0.17677669529663687f  // 1/(4*sqrt(2))

typedef __attribute__((ext_vector_type(8))) short short8;
typedef __attribute__((ext_vector_type(8))) unsigned short ushort8;
typedef __attribute__((ext_vector_type(4))) float f32x4;

// fp32 -> bf16 round-to-nearest-even
__device__ __forceinline__ unsigned short f2bf(float x) {
    union { float f; unsigned u; } v; v.f = x;
    unsigned r = v.u + 0x7fffu + ((v.u >> 16) & 1u);
    return (unsigned short)(r >> 16);
}
__device__ __forceinline__ float bf2f(unsigned short u) {
    union { unsigned u; float f; } v; v.u = ((unsigned)u) << 16;
    return v.f;
}

// ---------------- in-block split-K MFMA GEMM ----------------
// 512 threads: group g = waves 0-3 / 4-7 each computes the same 64x64 tile over half of K
// (K=384, 12 BK=32 steps, register-prefetch double-buffered LDS, one barrier/step),
// then group 1 dumps its partial to LDS and group 0 adds + stores. No atomics, no memset.
__device__ __forceinline__ void gemm_inblk_splitk(
    const float* __restrict__ A, const float* __restrict__ W,
    float* __restrict__ out, int row0, int n0, int outcol0, int ldw, int outld)
{
    __shared__ unsigned short Al[2][2][64][40];   // [group][buf]
    __shared__ unsigned short Bl[2][2][64][40];
    __shared__ float red[64][65];
    const int tid = threadIdx.x;            // 0..511
    const int g = tid >> 8;                 // K-group
    const int t = tid & 255;
    const int lane = t & 63, wave4 = t >> 6;
    const int wm = wave4 & 1, wn = wave4 >> 1;
    const int quad = lane >> 4, lr = lane & 15;
    const int k0base = g * 384;

    f32x4 acc[2][2] = {{{0.f,0.f,0.f,0.f},{0.f,0.f,0.f,0.f}},
                       {{0.f,0.f,0.f,0.f},{0.f,0.f,0.f,0.f}}};

    float4 ra[2], rb[2];
    #pragma unroll
    for (int l = 0; l < 2; ++l) {
        int idx = t + l * 256;
        ra[l] = *(const float4*)&A[(size_t)(row0 + (idx >> 3)) * 768 + k0base + (idx & 7) * 4];
        rb[l] = *(const float4*)&W[(size_t)(k0base + (idx >> 4)) * ldw + n0 + (idx & 15) * 4];
    }
    #pragma unroll
    for (int l = 0; l < 2; ++l) {
        int idx = t + l * 256;
        *(ushort4*)&Al[g][0][idx >> 3][(idx & 7) * 4] =
            make_ushort4(f2bf(ra[l].x), f2bf(ra[l].y), f2bf(ra[l].z), f2bf(ra[l].w));
        int kr = idx >> 4, nq = (idx & 15) * 4;
        int col = (((kr >> 3) ^ ((idx & 15) >> 2)) << 3) | (kr & 7);
        Bl[g][0][nq + 0][col] = f2bf(rb[l].x);
        Bl[g][0][nq + 1][col] = f2bf(rb[l].y);
        Bl[g][0][nq + 2][col] = f2bf(rb[l].z);
        Bl[g][0][nq + 3][col] = f2bf(rb[l].w);
    }
    __syncthreads();

    const int ITER = 12;   // 384 / 32
    #pragma unroll
    for (int i = 0; i < ITER; ++i) {
        const int cur = i & 1, nxt = cur ^ 1;
        float4 na[2], nb[2];
        if (i + 1 < ITER) {
            int kn = k0base + (i + 1) * 32;
            #pragma unroll
            for (int l = 0; l < 2; ++l) {
                int idx = t + l * 256;
                na[l] = *(const float4*)&A[(size_t)(row0 + (idx >> 3)) * 768 + kn + (idx & 7) * 4];
                nb[l] = *(const float4*)&W[(size_t)(kn + (idx >> 4)) * ldw + n0 + (idx & 15) * 4];
            }
        }
        short8 af[2], bfr[2];
        #pragma unroll
        for (int mi = 0; mi < 2; ++mi)
            af[mi] = *(const short8*)&Al[g][cur][wm * 32 + mi * 16 + lr][quad << 3];
        #pragma unroll
        for (int ni = 0; ni < 2; ++ni) {
            int csw = quad ^ ((wn * 2 + ni) & 3);
            bfr[ni] = *(const short8*)&Bl[g][cur][wn * 32 + ni * 16 + lr][csw << 3];
        }
        #pragma unroll
        for (int mi = 0; mi < 2; ++mi)
            #pragma unroll
            for (int ni = 0; ni < 2; ++ni)
                acc[mi][ni] = __builtin_amdgcn_mfma_f32_16x16x32_bf16(af[mi], bfr[ni], acc[mi][ni], 0, 0, 0);
        if (i + 1 < ITER) {
            #pragma unroll
            for (int l = 0; l < 2; ++l) {
                int idx = t + l * 256;
                *(ushort4*)&Al[g][nxt][idx >> 3][(idx & 7) * 4] =
                    make_ushort4(f2bf(na[l].x), f2bf(na[l].y), f2bf(na[l].z), f2bf(na[l].w));
                int kr = idx >> 4, nq = (idx & 15) * 4;
                int col = (((kr >> 3) ^ ((idx & 15) >> 2)) << 3) | (kr & 7);
                Bl[g][nxt][nq + 0][col] = f2bf(nb[l].x);
                Bl[g][nxt][nq + 1][col] = f2bf(nb[l].y);
                Bl[g][nxt][nq + 2][col] = f2bf(nb[l].z);
                Bl[g][nxt][nq + 3][col] = f2bf(nb[l].w);
            }
        }
        __syncthreads();
    }
    if (g == 1) {
        #pragma unroll
        for (int mi = 0; mi < 2; ++mi)
            #pragma unroll
            for (int ni = 0; ni < 2; ++ni)
                #pragma unroll
                for (int r = 0; r < 4; ++r)
                    red[wm * 32 + mi * 16 + quad * 4 + r][wn * 32 + ni * 16 + lr] = acc[mi][ni][r];
    }
    __syncthreads();
    if (g == 0) {
        #pragma unroll
        for (int mi = 0; mi < 2; ++mi)
            #pragma unroll
            for (int ni = 0; ni < 2; ++ni)
                #pragma unroll
                for (int r = 0; r < 4; ++r) {
                    int rr = wm * 32 + mi * 16 + quad * 4 + r;
                    int cc = wn * 32 + ni * 16 + lr;
                    out[(size_t)(row0 + rr) * outld + outcol0 + cc] = acc[mi][ni][r] + red[rr][cc];
                }
    }
}

// qkv: hidden(1024x768) @ [Wq|Wk|Wv] -> qkv(1024x1152). grid (18,16) x 512
__global__ __launch_bounds__(512) void gemm_qkv_mfma(
    const float* __restrict__ H, const float* __restrict__ Wq,
    const float* __restrict__ Wk, const float* __restrict__ Wv,
    float* __restrict__ out)
{
    const int nt = blockIdx.x, mt = blockIdx.y;
    const float* W; int ldw, n0;
    if (nt < 3)      { W = Wq; ldw = 192; n0 = nt * 64; }
    else if (nt < 6) { W = Wk; ldw = 192; n0 = (nt - 3) * 64; }
    else             { W = Wv; ldw = 768; n0 = (nt - 6) * 64; }
    gemm_inblk_splitk(H, W, out, mt * 64, n0, nt * 64, ldw, 1152);
}

// wo: y(1024x768) @ Wo(768x768) -> out(1024x768). grid (12,16) x 512
__global__ __launch_bounds__(512) void gemm_wo_mfma(
    const float* __restrict__ Y, const float* __restrict__ Wo, float* __restrict__ out)
{
    const int nt = blockIdx.x, mt = blockIdx.y;
    gemm_inblk_splitk(Y, Wo, out, mt * 64, nt * 64, nt * 64, 768, 768);
}

// ---------------- per-chunk state via MFMA -> S_T bf16 ----------------
// S_T[h][c][d][n] (ld=288, bf16): A = [V^T|ones] (m=80pad: d, row 64 = ones for z),
// B = phiK (n=320pad: feature). grid (16,12) x 256.
__global__ __launch_bounds__(256) void chunk_state_k(
    const float* __restrict__ qkv, unsigned short* __restrict__ St, float* __restrict__ z)
{
    const int c = blockIdx.x, h = blockIdx.y;
    __shared__ float Kc[64][17];
    __shared__ unsigned short Pk[320][72];
    __shared__ unsigned short Vt[80][72];
    const int tid = threadIdx.x;
    const int lane = tid & 63, wave = tid >> 6;
    const int quad = lane >> 4, lr = lane & 15;

    {
        int s = tid >> 2, f4 = (tid & 3) * 4;
        float4 kv = *(const float4*)&qkv[(size_t)(c * 64 + s) * 1152 + 192 + h * 16 + f4];
        Kc[s][f4 + 0] = kv.x; Kc[s][f4 + 1] = kv.y; Kc[s][f4 + 2] = kv.z; Kc[s][f4 + 3] = kv.w;
    }
    #pragma unroll
    for (int l = 0; l < 4; ++l) {
        int idx = tid + l * 256;
        int s = idx >> 4, d4 = (idx & 15) * 4;
        float4 vv = *(const float4*)&qkv[(size_t)(c * 64 + s) * 1152 + 384 + h * 64 + d4];
        Vt[d4 + 0][s] = f2bf(vv.x);
        Vt[d4 + 1][s] = f2bf(vv.y);
        Vt[d4 + 2][s] = f2bf(vv.z);
        Vt[d4 + 3][s] = f2bf(vv.w);
    }
    for (int idx = tid; idx < 16 * 72; idx += 256) {
        int rr = 64 + idx / 72, ss = idx % 72;
        Vt[rr][ss] = (rr == 64 && ss < 64) ? (unsigned short)0x3F80 : (unsigned short)0;
    }
    __syncthreads();
    for (int idx = tid; idx < 2880; idx += 256) {
        int n = idx / 9, s8 = (idx % 9) * 8;
        short8 v8;
        #pragma unroll
        for (int tt = 0; tt < 8; ++tt) {
            int s = s8 + tt;
            float ph = 0.f;
            if (s < 64 && n < 273) {
                if (n == 0) ph = 1.f;
                else if (n < 17) ph = Kc[s][n - 1] * 0.5f;
                else { int m = n - 17; ph = Kc[s][m >> 4] * Kc[s][m & 15] * C2; }
            }
            v8[tt] = (short)f2bf(ph);
        }
        *(short8*)&Pk[n][s8] = v8;
    }
    __syncthreads();

    f32x4 acc[5][5];
    #pragma unroll
    for (int a = 0; a < 5; ++a)
        #pragma unroll
        for (int b = 0; b < 5; ++b) acc[a][b] = (f32x4){0.f, 0.f, 0.f, 0.f};
    #pragma unroll
    for (int ks = 0; ks < 2; ++ks) {
        short8 af[5], bfr[5];
        #pragma unroll
        for (int mt = 0; mt < 5; ++mt)              // A side: d (Vt)
            af[mt] = *(const short8*)&Vt[mt * 16 + lr][ks * 32 + quad * 8];
        #pragma unroll
        for (int nt = 0; nt < 5; ++nt)              // B side: feature n (Pk)
            bfr[nt] = *(const short8*)&Pk[(wave * 5 + nt) * 16 + lr][ks * 32 + quad * 8];
        #pragma unroll
        for (int mt = 0; mt < 5; ++mt)
            #pragma unroll
            for (int nt = 0; nt < 5; ++nt)
                acc[mt][nt] = __builtin_amdgcn_mfma_f32_16x16x32_bf16(af[mt], bfr[nt], acc[mt][nt], 0, 0, 0);
    }
    unsigned short* Sbt = St + (size_t)(h * 16 + c) * 18432;
    float* zb = z + (h * 16 + c) * 273;
    #pragma unroll
    for (int nt = 0; nt < 5; ++nt) {
        int n = (wave * 5 + nt) * 16 + lr;
        if (n < 273) {
            #pragma unroll
            for (int mt = 0; mt < 4; ++mt)
                #pragma unroll
                for (int r = 0; r < 4; ++r)
                    Sbt[(mt * 16 + quad * 4 + r) * 288 + n] = f2bf(acc[mt][nt][r]);
            if (quad == 0) zb[n] = acc[4][nt][0];   // d==64 ones-row -> z
        }
    }
}

// ---------------- exclusive prefix over 16 chunks (in place; S bf16, z fp32) ----------------
__global__ __launch_bounds__(256) void scan_state_k(unsigned short* __restrict__ St, float* __restrict__ z)
{
    const int NS = 12 * 64 * 273;   // 209,664
    int e = blockIdx.x * 256 + threadIdx.x;
    if (e < NS) {
        int hh = e / (64 * 273), rem = e % (64 * 273);
        int d = rem / 273, n = rem % 273;
        unsigned short* p = St + (size_t)hh * 16 * 18432 + d * 288 + n;
        float run = 0.f;
        #pragma unroll
        for (int c = 0; c < 16; ++c) {
            float v = bf2f(p[c * 18432]);
            p[c * 18432] = f2bf(run);
            run += v;
        }
    } else if (e < NS + 12 * 273) {
        int e2 = e - NS, hh = e2 / 273, n = e2 % 273;
        float* p = z + hh * 16 * 273 + n;
        float run = 0.f;
        #pragma unroll
        for (int c = 0; c < 16; ++c) { float v = p[c * 273]; p[c * 273] = run; run += v; }
    }
}

// ---------------- per-chunk output via ONE fused MFMA GEMM ----------------
__global__ __launch_bounds__(256) void chunk_out_k(
    const float* __restrict__ qkv, const unsigned short* __restrict__ St, const float* __restrict__ z,
    float* __restrict__ y)
{
    const int c = blockIdx.x, h = blockIdx.y;
    __shared__ float Qc[64][17];
    __shared__ unsigned short Aq[64][40];
    __shared__ unsigned short Kb[64][40];
    __shared__ unsigned short Pq[64][360];
    __shared__ unsigned short Sv[64][360];
    __shared__ float zl[288];
    __shared__ float dpart[6][64];
    const int tid = threadIdx.x;
    const int lane = tid & 63, wave = tid >> 6;
    const int wm = wave & 1, wn = wave >> 1;
    const int quad = lane >> 4, lr = lane & 15;

    {
        int s = tid >> 2, f4 = (tid & 3) * 4;
        const float* base = &qkv[(size_t)(c * 64 + s) * 1152 + h * 16];
        float4 qv = *(const float4*)&base[f4];
        float4 kv = *(const float4*)&base[192 + f4];
        Qc[s][f4 + 0] = qv.x; Qc[s][f4 + 1] = qv.y; Qc[s][f4 + 2] = qv.z; Qc[s][f4 + 3] = qv.w;
        *(ushort4*)&Aq[s][f4] = make_ushort4(f2bf(qv.x), f2bf(qv.y), f2bf(qv.z), f2bf(qv.w));
        *(ushort4*)&Kb[s][f4] = make_ushort4(f2bf(kv.x), f2bf(kv.y), f2bf(kv.z), f2bf(kv.w));
        *(ushort4*)&Aq[s][16 + (tid & 3) * 4] = make_ushort4(0, 0, 0, 0);
        *(ushort4*)&Kb[s][16 + (tid & 3) * 4] = make_ushort4(0, 0, 0, 0);
    }
    #pragma unroll
    for (int l = 0; l < 4; ++l) {                    // V -> Sv cols 288..351
        int idx = tid + l * 256;
        int s = idx >> 4, d4 = (idx & 15) * 4;
        float4 vv = *(const float4*)&qkv[(size_t)(c * 64 + s) * 1152 + 384 + h * 64 + d4];
        Sv[d4 + 0][288 + s] = f2bf(vv.x);
        Sv[d4 + 1][288 + s] = f2bf(vv.y);
        Sv[d4 + 2][288 + s] = f2bf(vv.z);
        Sv[d4 + 3][288 + s] = f2bf(vv.w);
    }
    // S_T (bf16) rows -> Sv cols 0..272 via straight vector copies
    const unsigned short* Sgt = St + (size_t)(h * 16 + c) * 18432;
    for (int idx = tid; idx < 64 * 34; idx += 256) {       // n 0..271
        int d = idx / 34, n8 = (idx % 34) * 8;
        *(ushort8*)&Sv[d][n8] = *(const ushort8*)&Sgt[d * 288 + n8];
    }
    for (int idx = tid; idx < 64; idx += 256) Sv[idx][272] = Sgt[idx * 288 + 272];
    for (int idx = tid; idx < 64 * 15; idx += 256) {       // zero n 273..287
        int d = idx / 15, n = 273 + idx % 15;
        Sv[d][n] = 0;
    }
    const float* zg = z + (h * 16 + c) * 273;
    for (int idx = tid; idx < 288; idx += 256) zl[idx] = (idx < 273) ? zg[idx] : 0.f;
    __syncthreads();

    f32x4 accS[2][2] = {{{0.f,0.f,0.f,0.f},{0.f,0.f,0.f,0.f}},
                        {{0.f,0.f,0.f,0.f},{0.f,0.f,0.f,0.f}}};
    {
        short8 af[2], bfr[2];
        #pragma unroll
        for (int mi = 0; mi < 2; ++mi)
            af[mi] = *(const short8*)&Aq[wm * 32 + mi * 16 + lr][quad * 8];
        #pragma unroll
        for (int ni = 0; ni < 2; ++ni)
            bfr[ni] = *(const short8*)&Kb[wn * 32 + ni * 16 + lr][quad * 8];
        #pragma unroll
        for (int mi = 0; mi < 2; ++mi)
            #pragma unroll
            for (int ni = 0; ni < 2; ++ni)
                accS[mi][ni] = __builtin_amdgcn_mfma_f32_16x16x32_bf16(af[mi], bfr[ni], accS[mi][ni], 0, 0, 0);
    }

    {
        int i = lane;
        float qr[16];
        #pragma unroll
        for (int f = 0; f < 16; ++f) qr[f] = Qc[i][f];
        float dp = 0.f;
        int n0 = wave * 72;
        for (int n = n0; n < n0 + 72; ++n) {
            float ph;
            if (n == 0) ph = 1.f;
            else if (n < 17) ph = qr[n - 1] * 0.5f;
            else if (n < 273) { int m = n - 17; ph = qr[m >> 4] * qr[m & 15] * C2; }
            else ph = 0.f;
            Pq[i][n] = f2bf(ph);
            dp += ph * zl[n];
        }
        dpart[wave][i] = dp;
    }

    #pragma unroll
    for (int mi = 0; mi < 2; ++mi) {
        float rs[4] = {0.f, 0.f, 0.f, 0.f};
        #pragma unroll
        for (int ni = 0; ni < 2; ++ni)
            #pragma unroll
            for (int r = 0; r < 4; ++r) {
                int i = wm * 32 + mi * 16 + quad * 4 + r;
                int j = wn * 32 + ni * 16 + lr;
                float u = accS[mi][ni][r];
                float sc = (j <= i) ? (1.f + 0.25f * u + u * u * (1.f / 32.f)) : 0.f;
                rs[r] += sc;
                Pq[i][288 + j] = f2bf(sc);
            }
        #pragma unroll
        for (int r = 0; r < 4; ++r) {
            float v = rs[r];
            v += __shfl_xor(v, 1);
            v += __shfl_xor(v, 2);
            v += __shfl_xor(v, 4);
            v += __shfl_xor(v, 8);
            if (lr == 0) dpart[4 + wn][wm * 32 + mi * 16 + quad * 4 + r] = v;
        }
    }
    __syncthreads();

    f32x4 acc[2][2] = {{{0.f,0.f,0.f,0.f},{0.f,0.f,0.f,0.f}},
                       {{0.f,0.f,0.f,0.f},{0.f,0.f,0.f,0.f}}};
    #pragma unroll
    for (int ks = 0; ks < 11; ++ks) {
        short8 af[2], bfr[2];
        #pragma unroll
        for (int mi = 0; mi < 2; ++mi)
            af[mi] = *(const short8*)&Pq[wm * 32 + mi * 16 + lr][ks * 32 + quad * 8];
        #pragma unroll
        for (int ni = 0; ni < 2; ++ni)
            bfr[ni] = *(const short8*)&Sv[wn * 32 + ni * 16 + lr][ks * 32 + quad * 8];
        #pragma unroll
        for (int mi = 0; mi < 2; ++mi)
            #pragma unroll
            for (int ni = 0; ni < 2; ++ni)
                acc[mi][ni] = __builtin_amdgcn_mfma_f32_16x16x32_bf16(af[mi], bfr[ni], acc[mi][ni], 0, 0, 0);
    }

    #pragma unroll
    for (int mi = 0; mi < 2; ++mi)
        #pragma unroll
        for (int r = 0; r < 4; ++r) {
            int i = wm * 32 + mi * 16 + quad * 4 + r;
            float den = dpart[0][i] + dpart[1][i] + dpart[2][i] +
                        dpart[3][i] + dpart[4][i] + dpart[5][i] + 1e-12f;
            float rden = 1.f / den;
            #pragma unroll
            for (int ni = 0; ni < 2; ++ni)
                y[(size_t)(c * 64 + i) * 768 + h * 64 + wn * 32 + ni * 16 + lr] = acc[mi][ni][r] * rden;
        }
}

extern "C" void kernel_launch(void* const* d_in, const int* in_sizes, int n_in,
                              void* d_out, int out_size, void* d_ws, size_t ws_size,
                              hipStream_t stream) {
    const float* hs = (const float*)d_in[0];
    const float* Wq = (const float*)d_in[1];
    const float* Wk = (const float*)d_in[2];
    const float* Wv = (const float*)d_in[3];
    const float* Wo = (const float*)d_in[4];
    float* out = (float*)d_out;
    float* ws  = (float*)d_ws;

    // Workspace layout (slot sizes derived R3; St now bf16 S_T[12*16][64][288] = 7.08 MB
    // inside the old 13.4 MB Sb slot — zb offset unchanged).
    float* qkv = ws;                                        // 1024*1152 floats
    float* yb  = ws + 1179648;                              // 1024*768
    unsigned short* St = (unsigned short*)(ws + 1966080);   // 12*16*64*288 ushorts
    float* zb  = ws + 5320704;                              // 12*16*273

    gemm_qkv_mfma<<<dim3(18, 16), 512, 0, stream>>>(hs, Wq, Wk, Wv, qkv);
    chunk_state_k<<<dim3(16, 12), 256, 0, stream>>>(qkv, St, zb);
    scan_state_k <<<832, 256, 0, stream>>>(St, zb);
    chunk_out_k  <<<dim3(16, 12), 256, 0, stream>>>(qkv, St, zb, yb);
    gemm_wo_mfma <<<dim3(12, 16), 512, 0, stream>>>(yb, Wo, out);
}